// Round 2
// baseline (5994.988 us; speedup 1.0000x reference)
//
#include <hip/hip_runtime.h>

#define Hd 256
#define NNODE 10000
#define NE1 131072
#define NE2 65536
#define ENC_CHUNK 16384

#define BM 64
#define BN 64
#define BK 16

__device__ __forceinline__ float b2f(ushort u) { return __uint_as_float(((unsigned)u) << 16); }
__device__ __forceinline__ ushort f2b(float f) {
  unsigned u = __float_as_uint(f);
  return (ushort)((u + 0x7fffu + ((u >> 16) & 1u)) >> 16);
}
__device__ __forceinline__ int fenc(float x) {
  int i = __float_as_int(x);
  return i >= 0 ? i : (i ^ 0x7fffffff);
}
__device__ __forceinline__ float fdec(int i) {
  return __int_as_float(i >= 0 ? i : (i ^ 0x7fffffff));
}

// ---------------- small kernels ----------------

__global__ void time_mlp_k(const float* __restrict__ tval,
                           const float* __restrict__ W0, const float* __restrict__ b0,
                           const float* __restrict__ W1, const float* __restrict__ b1,
                           const float* __restrict__ W2, const float* __restrict__ b2,
                           float* __restrict__ tenc) {
  __shared__ float h0[Hd], h1[Hd];
  int b = blockIdx.x, j = threadIdx.x;
  float t = tval[b];
  h0[j] = fmaxf(t * W0[j] + b0[j], 0.f);
  __syncthreads();
  float a = b1[j];
  for (int k = 0; k < Hd; ++k) a += h0[k] * W1[k * Hd + j];
  h1[j] = fmaxf(a, 0.f);
  __syncthreads();
  float c = b2[j];
  for (int k = 0; k < Hd; ++k) c += h1[k] * W2[k * Hd + j];
  tenc[b * Hd + j] = c;
}

// x0[n][j] = tenc[batch[n]][j mod 256], j in [0,512)
__global__ void build_x0_k(const int* __restrict__ batch, const float* __restrict__ tenc,
                           float* __restrict__ x0) {
  int idx = blockIdx.x * 256 + threadIdx.x;
  int n = idx >> 9, j = idx & 511;
  x0[idx] = tenc[batch[n] * Hd + (j & 255)];
}

// first edge-encoder layer (chunked): out[r][j] = relu(attr[r]*W0[j]+b0[j])
__global__ void enc_h0_k(const float* __restrict__ attr, const float* __restrict__ W0,
                         const float* __restrict__ b0, float* __restrict__ out) {
  int e = blockIdx.x, j = threadIdx.x;
  out[(size_t)e * Hd + j] = fmaxf(attr[e] * W0[j] + b0[j], 0.f);
}

__global__ void init_xnext_k(float* __restrict__ xn, const float* __restrict__ b1,
                             const float* __restrict__ b2) {
  int idx = blockIdx.x * 256 + threadIdx.x;
  int j = idx & 511;
  xn[idx] = (j < 256) ? b1[j] : b2[j - 256];
}

__global__ void init_seg_k(int* __restrict__ segmax, float* __restrict__ denom) {
  int i = blockIdx.x * 256 + threadIdx.x;
  if (i < NNODE) {
    segmax[i] = fenc(-__int_as_float(0x7f800000));
    denom[i] = 0.f;
  }
}

__global__ void attn_expsum_k(float* __restrict__ logits, const int* __restrict__ dst,
                              const int* __restrict__ segmax, float* __restrict__ denom, int E) {
  int e = blockIdx.x * 256 + threadIdx.x;
  if (e < E) {
    int d = dst[e];
    float ex = __expf(logits[e] - fdec(segmax[d]));
    logits[e] = ex;
    atomicAdd(denom + d, ex);
  }
}

__global__ void attn_scatter_k(const float* __restrict__ xl, const float* __restrict__ ex,
                               const float* __restrict__ denom, const int* __restrict__ src,
                               const int* __restrict__ dst, float* __restrict__ xnext,
                               int colbase, int E) {
  int e = blockIdx.x, j = threadIdx.x;
  int s = src[e], d = dst[e];
  float alpha = ex[e] / (denom[d] + 1e-16f);
  atomicAdd(xnext + (size_t)d * 512 + colbase + j, xl[(size_t)s * Hd + j] * alpha);
}

// ---------------- tiled fp32 GEMM (A fp32, W fp32, out fp32 or bf16) ----------------
// C[M,256] = op(A[M,K] @ W[K,256] + bias)
template <bool RELU, bool OBF16>
__global__ __launch_bounds__(256) void gemm_kernel(
    const float* __restrict__ A, const float* __restrict__ W, const float* __restrict__ bias,
    void* __restrict__ C, int M, int K, int lda, int ldc) {
  __shared__ float As[BK][BM + 4];
  __shared__ float Bs[BK][BN + 4];
  const int tid = threadIdx.x;
  const int m0 = blockIdx.x * BM;
  const int n0 = blockIdx.y * BN;
  const int tx = tid & 15;
  const int ty = tid >> 4;
  const int ar = tid >> 2;
  const int ac = (tid & 3) << 2;
  const int wr = tid >> 4;
  const int wc = (tid & 15) << 2;
  const int am = m0 + ar;
  float acc[4][4] = {};
  for (int k0 = 0; k0 < K; k0 += BK) {
    float4 av = make_float4(0.f, 0.f, 0.f, 0.f);
    if (am < M) av = *(const float4*)(A + (size_t)am * lda + k0 + ac);
    As[ac + 0][ar] = av.x;
    As[ac + 1][ar] = av.y;
    As[ac + 2][ar] = av.z;
    As[ac + 3][ar] = av.w;
    *(float4*)&Bs[wr][wc] = *(const float4*)(W + (size_t)(k0 + wr) * 256 + n0 + wc);
    __syncthreads();
#pragma unroll
    for (int kk = 0; kk < BK; ++kk) {
      float4 a = *(const float4*)&As[kk][ty << 2];
      float4 b = *(const float4*)&Bs[kk][tx << 2];
      acc[0][0] += a.x * b.x; acc[0][1] += a.x * b.y; acc[0][2] += a.x * b.z; acc[0][3] += a.x * b.w;
      acc[1][0] += a.y * b.x; acc[1][1] += a.y * b.y; acc[1][2] += a.y * b.z; acc[1][3] += a.y * b.w;
      acc[2][0] += a.z * b.x; acc[2][1] += a.z * b.y; acc[2][2] += a.z * b.z; acc[2][3] += a.z * b.w;
      acc[3][0] += a.w * b.x; acc[3][1] += a.w * b.y; acc[3][2] += a.w * b.z; acc[3][3] += a.w * b.w;
    }
    __syncthreads();
  }
  int nb = n0 + (tx << 2);
  float bv[4] = {bias[nb], bias[nb + 1], bias[nb + 2], bias[nb + 3]};
#pragma unroll
  for (int i = 0; i < 4; ++i) {
    int m = m0 + (ty << 2) + i;
    if (m < M) {
      float v0 = acc[i][0] + bv[0], v1 = acc[i][1] + bv[1];
      float v2 = acc[i][2] + bv[2], v3 = acc[i][3] + bv[3];
      if (RELU) {
        v0 = fmaxf(v0, 0.f); v1 = fmaxf(v1, 0.f);
        v2 = fmaxf(v2, 0.f); v3 = fmaxf(v3, 0.f);
      }
      if (!OBF16) {
        float4 v = make_float4(v0, v1, v2, v3);
        *(float4*)((float*)C + (size_t)m * ldc + nb) = v;
      } else {
        ushort4 v;
        v.x = f2b(v0); v.y = f2b(v1); v.z = f2b(v2); v.w = f2b(v3);
        *(ushort4*)((ushort*)C + (size_t)m * ldc + nb) = v;
      }
    }
  }
}

// ---------------- fused attention logits: leakyrelu(xl[src]+xr[dst]+e@We)@att ----------------
// grid: E/64, block 256. eenc bf16 E x 256, We fp32 256x256.
__global__ __launch_bounds__(256) void attn_fused_k(
    const ushort* __restrict__ eenc, const float* __restrict__ We,
    const float* __restrict__ att, const float* __restrict__ xl,
    const float* __restrict__ xr, const int* __restrict__ src,
    const int* __restrict__ dst, float* __restrict__ logits,
    int* __restrict__ segmax) {
  __shared__ float Bs[16][256 + 4];
  __shared__ ushort As[16][64 + 2];
  __shared__ float red[64][17];
  const int tid = threadIdx.x;
  const int tx = tid & 15, ty = tid >> 4;
  const int m0 = blockIdx.x * 64;
  const int sr = tid >> 2;            // A-stage row 0..63
  const int skc = (tid & 3) << 2;     // A-stage k offset 0,4,8,12
  const int br = tid >> 4;            // B-stage row 0..15
  const int bc = (tid & 15) << 4;     // B-stage col 0..240
  float acc[4][16] = {};
  for (int k0 = 0; k0 < 256; k0 += 16) {
    ushort4 av = *(const ushort4*)(eenc + (size_t)(m0 + sr) * 256 + k0 + skc);
    As[skc + 0][sr] = av.x; As[skc + 1][sr] = av.y;
    As[skc + 2][sr] = av.z; As[skc + 3][sr] = av.w;
    const float* bp = We + (size_t)(k0 + br) * 256 + bc;
#pragma unroll
    for (int q = 0; q < 4; ++q)
      *(float4*)&Bs[br][bc + 4 * q] = *(const float4*)(bp + 4 * q);
    __syncthreads();
#pragma unroll
    for (int kk = 0; kk < 16; ++kk) {
      float a[4];
#pragma unroll
      for (int i = 0; i < 4; ++i) a[i] = b2f(As[kk][(ty << 2) + i]);
      float b[16];
#pragma unroll
      for (int j = 0; j < 16; ++j) b[j] = Bs[kk][tx + 16 * j];
#pragma unroll
      for (int i = 0; i < 4; ++i)
#pragma unroll
        for (int j = 0; j < 16; ++j) acc[i][j] += a[i] * b[j];
    }
    __syncthreads();
  }
#pragma unroll
  for (int i = 0; i < 4; ++i) {
    int e = m0 + (ty << 2) + i;
    int s = src[e], d = dst[e];
    const float* pl = xl + (size_t)s * Hd;
    const float* pr = xr + (size_t)d * Hd;
    float ps = 0.f;
#pragma unroll
    for (int j = 0; j < 16; ++j) {
      int c = tx + 16 * j;
      float v = acc[i][j] + pl[c] + pr[c];
      v = v > 0.f ? v : 0.2f * v;
      ps += v * att[c];
    }
    red[(ty << 2) + i][tx] = ps;
  }
  __syncthreads();
  if (tid < 64) {
    float s = 0.f;
#pragma unroll
    for (int c = 0; c < 16; ++c) s += red[tid][c];
    int e = m0 + tid;
    logits[e] = s;
    atomicMax(segmax + dst[e], fenc(s));
  }
}

// ---------------- fused decoder: relu(relu([x_s|x_d|e1]@W0+b0)@W1+b1)@W2+b2 ----------------
// grid: E1/64, block 256.
__global__ __launch_bounds__(256) void dec_fused_k(
    const float* __restrict__ x, const ushort* __restrict__ e1,
    const float* __restrict__ W0, const float* __restrict__ b0,
    const float* __restrict__ W1, const float* __restrict__ b1,
    const float* __restrict__ W2, const float* __restrict__ b2,
    const int* __restrict__ src, const int* __restrict__ dst,
    float* __restrict__ out) {
  __shared__ float h0[64][257];
  __shared__ float Bs[16][256 + 4];
  __shared__ float As[16][64 + 1];
  const int tid = threadIdx.x;
  const int tx = tid & 15, ty = tid >> 4;
  const int m0 = blockIdx.x * 64;
  const int sr = tid >> 2;
  const int skc = (tid & 3) << 2;
  const int br = tid >> 4;
  const int bc = (tid & 15) << 4;
  const int gs = src[m0 + sr];
  const int gd = dst[m0 + sr];
  float acc[4][16] = {};
  // phase 1: h0 = relu(gathered[1280] @ W0 + b0)
  for (int k0 = 0; k0 < 1280; k0 += 16) {
    int k = k0 + skc;
    float4 av;
    if (k < 512) {
      av = *(const float4*)(x + (size_t)gs * 512 + k);
    } else if (k < 1024) {
      av = *(const float4*)(x + (size_t)gd * 512 + (k - 512));
    } else {
      ushort4 u = *(const ushort4*)(e1 + (size_t)(m0 + sr) * 256 + (k - 1024));
      av = make_float4(b2f(u.x), b2f(u.y), b2f(u.z), b2f(u.w));
    }
    As[skc + 0][sr] = av.x; As[skc + 1][sr] = av.y;
    As[skc + 2][sr] = av.z; As[skc + 3][sr] = av.w;
    const float* bp = W0 + (size_t)(k0 + br) * 256 + bc;
#pragma unroll
    for (int q = 0; q < 4; ++q)
      *(float4*)&Bs[br][bc + 4 * q] = *(const float4*)(bp + 4 * q);
    __syncthreads();
#pragma unroll
    for (int kk = 0; kk < 16; ++kk) {
      float a[4];
#pragma unroll
      for (int i = 0; i < 4; ++i) a[i] = As[kk][(ty << 2) + i];
      float b[16];
#pragma unroll
      for (int j = 0; j < 16; ++j) b[j] = Bs[kk][tx + 16 * j];
#pragma unroll
      for (int i = 0; i < 4; ++i)
#pragma unroll
        for (int j = 0; j < 16; ++j) acc[i][j] += a[i] * b[j];
    }
    __syncthreads();
  }
#pragma unroll
  for (int i = 0; i < 4; ++i)
#pragma unroll
    for (int j = 0; j < 16; ++j) {
      int c = tx + 16 * j;
      h0[(ty << 2) + i][c] = fmaxf(acc[i][j] + b0[c], 0.f);
    }
  __syncthreads();
  // phase 2: h1 = relu(h0 @ W1 + b1); rowdot = h1 . W2
  float acc2[4][16] = {};
  for (int k0 = 0; k0 < 256; k0 += 16) {
    const float* bp = W1 + (size_t)(k0 + br) * 256 + bc;
#pragma unroll
    for (int q = 0; q < 4; ++q)
      *(float4*)&Bs[br][bc + 4 * q] = *(const float4*)(bp + 4 * q);
    __syncthreads();
#pragma unroll
    for (int kk = 0; kk < 16; ++kk) {
      float a[4];
#pragma unroll
      for (int i = 0; i < 4; ++i) a[i] = h0[(ty << 2) + i][k0 + kk];
      float b[16];
#pragma unroll
      for (int j = 0; j < 16; ++j) b[j] = Bs[kk][tx + 16 * j];
#pragma unroll
      for (int i = 0; i < 4; ++i)
#pragma unroll
        for (int j = 0; j < 16; ++j) acc2[i][j] += a[i] * b[j];
    }
    __syncthreads();
  }
  float part[4];
#pragma unroll
  for (int i = 0; i < 4; ++i) {
    float ps = 0.f;
#pragma unroll
    for (int j = 0; j < 16; ++j) {
      int c = tx + 16 * j;
      float v = fmaxf(acc2[i][j] + b1[c], 0.f);
      ps += v * W2[c];
    }
    part[i] = ps;
  }
  float* red = (float*)Bs;  // 64*17 = 1088 <= 16*260
#pragma unroll
  for (int i = 0; i < 4; ++i) red[((ty << 2) + i) * 17 + tx] = part[i];
  __syncthreads();
  if (tid < 64) {
    float s = 0.f;
#pragma unroll
    for (int c = 0; c < 16; ++c) s += red[tid * 17 + c];
    out[m0 + tid] = s + b2[0];
  }
}

// ---------------- launch helpers ----------------

static inline void gemm_f32(hipStream_t s, const float* A, const float* W, const float* bias,
                            float* C, int M, int K, int lda, bool relu) {
  dim3 g((M + BM - 1) / BM, Hd / BN);
  if (relu)
    gemm_kernel<true, false><<<g, 256, 0, s>>>(A, W, bias, C, M, K, lda, Hd);
  else
    gemm_kernel<false, false><<<g, 256, 0, s>>>(A, W, bias, C, M, K, lda, Hd);
}

static inline void gemm_bf16out(hipStream_t s, const float* A, const float* W, const float* bias,
                                ushort* C, int M, int K, int lda) {
  dim3 g((M + BM - 1) / BM, Hd / BN);
  gemm_kernel<false, true><<<g, 256, 0, s>>>(A, W, bias, C, M, K, lda, Hd);
}

extern "C" void kernel_launch(void* const* d_in, const int* in_sizes, int n_in,
                              void* d_out, int out_size, void* d_ws, size_t ws_size,
                              hipStream_t stream) {
  const int*   eidx1  = (const int*)d_in[0];
  const float* eattr1 = (const float*)d_in[1];
  const int*   eidx2  = (const int*)d_in[2];
  const float* eattr2 = (const float*)d_in[3];
  const int*   batch  = (const int*)d_in[4];
  const float* tval   = (const float*)d_in[5];
  const float* te_W0 = (const float*)d_in[6];
  const float* te_b0 = (const float*)d_in[7];
  const float* te_W1 = (const float*)d_in[8];
  const float* te_b1 = (const float*)d_in[9];
  const float* te_W2 = (const float*)d_in[10];
  const float* te_b2 = (const float*)d_in[11];
  const float* ee_W0 = (const float*)d_in[12];
  const float* ee_b0 = (const float*)d_in[13];
  const float* ee_W1 = (const float*)d_in[14];
  const float* ee_b1 = (const float*)d_in[15];
  const float* ee_W2 = (const float*)d_in[16];
  const float* ee_b2 = (const float*)d_in[17];
  const float* dec_W0 = (const float*)d_in[18];
  const float* dec_b0 = (const float*)d_in[19];
  const float* dec_W1 = (const float*)d_in[20];
  const float* dec_b1 = (const float*)d_in[21];
  const float* dec_W2 = (const float*)d_in[22];
  const float* dec_b2 = (const float*)d_in[23];
  const float* gg_Wl  = (const float*)d_in[24];
  const float* gg_bl  = (const float*)d_in[25];
  const float* gg_Wr  = (const float*)d_in[26];
  const float* gg_br  = (const float*)d_in[27];
  const float* gg_We  = (const float*)d_in[28];
  const float* gg_att = (const float*)d_in[29];
  const float* gg_bias= (const float*)d_in[30];
  const float* gf_Wl  = (const float*)d_in[31];
  const float* gf_bl  = (const float*)d_in[32];
  const float* gf_Wr  = (const float*)d_in[33];
  const float* gf_br  = (const float*)d_in[34];
  const float* gf_We  = (const float*)d_in[35];
  const float* gf_att = (const float*)d_in[36];
  const float* gf_bias= (const float*)d_in[37];
  (void)in_sizes; (void)n_in; (void)out_size; (void)ws_size;

  const int* src1 = eidx1;
  const int* dst1 = eidx1 + NE1;
  const int* src2 = eidx2;
  const int* dst2 = eidx2 + NE2;

  char* base = (char*)d_ws;
  size_t off = 0;
  auto alloc = [&](size_t bytes) {
    void* p = base + off;
    off += (bytes + 255) & ~(size_t)255;
    return p;
  };
  float*  x_a    = (float*)alloc((size_t)NNODE * 512 * 4);   // 20.5 MB
  float*  x_b    = (float*)alloc((size_t)NNODE * 512 * 4);   // 20.5 MB
  float*  xl     = (float*)alloc((size_t)NNODE * Hd * 4);    // 10.2 MB
  float*  xr     = (float*)alloc((size_t)NNODE * Hd * 4);    // 10.2 MB
  ushort* e1     = (ushort*)alloc((size_t)NE1 * Hd * 2);     // 67.1 MB
  ushort* e2     = (ushort*)alloc((size_t)NE2 * Hd * 2);     // 33.6 MB
  float*  logits = (float*)alloc((size_t)NE1 * 4);           // 0.5 MB
  float*  denom  = (float*)alloc((size_t)NNODE * 4);
  int*    segmax = (int*)alloc((size_t)NNODE * 4);
  float*  tenc   = (float*)alloc((size_t)16 * Hd * 4);

  float* out = (float*)d_out;

  // ---- edge encoder, chunked through x_a/x_b (not yet live) ----
  for (int c = 0; c < NE1 / ENC_CHUNK; ++c) {
    enc_h0_k<<<ENC_CHUNK, 256, 0, stream>>>(eattr1 + (size_t)c * ENC_CHUNK, ee_W0, ee_b0, x_a);
    gemm_f32(stream, x_a, ee_W1, ee_b1, x_b, ENC_CHUNK, Hd, Hd, true);
    gemm_bf16out(stream, x_b, ee_W2, ee_b2, e1 + (size_t)c * ENC_CHUNK * Hd, ENC_CHUNK, Hd, Hd);
  }
  for (int c = 0; c < NE2 / ENC_CHUNK; ++c) {
    enc_h0_k<<<ENC_CHUNK, 256, 0, stream>>>(eattr2 + (size_t)c * ENC_CHUNK, ee_W0, ee_b0, x_a);
    gemm_f32(stream, x_a, ee_W1, ee_b1, x_b, ENC_CHUNK, Hd, Hd, true);
    gemm_bf16out(stream, x_b, ee_W2, ee_b2, e2 + (size_t)c * ENC_CHUNK * Hd, ENC_CHUNK, Hd, Hd);
  }

  // ---- time encoding -> x0 ----
  time_mlp_k<<<16, 256, 0, stream>>>(tval, te_W0, te_b0, te_W1, te_b1, te_W2, te_b2, tenc);
  build_x0_k<<<(NNODE * 512) / 256, 256, 0, stream>>>(batch, tenc, x_a);

  float* x_cur = x_a;
  float* x_nxt = x_b;
  for (int i = 0; i < 3; ++i) {
    init_xnext_k<<<(NNODE * 512) / 256, 256, 0, stream>>>(x_nxt, gg_bias + i * Hd, gf_bias + i * Hd);
    // ---- graph 1 ----
    gemm_f32(stream, x_cur, gg_Wl + (size_t)i * 512 * Hd, gg_bl + i * Hd, xl, NNODE, 512, 512, false);
    gemm_f32(stream, x_cur, gg_Wr + (size_t)i * 512 * Hd, gg_br + i * Hd, xr, NNODE, 512, 512, false);
    init_seg_k<<<(NNODE + 255) / 256, 256, 0, stream>>>(segmax, denom);
    attn_fused_k<<<NE1 / 64, 256, 0, stream>>>(e1, gg_We + (size_t)i * Hd * Hd, gg_att + i * Hd,
                                               xl, xr, src1, dst1, logits, segmax);
    attn_expsum_k<<<NE1 / 256, 256, 0, stream>>>(logits, dst1, segmax, denom, NE1);
    attn_scatter_k<<<NE1, 256, 0, stream>>>(xl, logits, denom, src1, dst1, x_nxt, 0, NE1);
    // ---- graph 2 ----
    gemm_f32(stream, x_cur, gf_Wl + (size_t)i * 512 * Hd, gf_bl + i * Hd, xl, NNODE, 512, 512, false);
    gemm_f32(stream, x_cur, gf_Wr + (size_t)i * 512 * Hd, gf_br + i * Hd, xr, NNODE, 512, 512, false);
    init_seg_k<<<(NNODE + 255) / 256, 256, 0, stream>>>(segmax, denom);
    attn_fused_k<<<NE2 / 64, 256, 0, stream>>>(e2, gf_We + (size_t)i * Hd * Hd, gf_att + i * Hd,
                                               xl, xr, src2, dst2, logits, segmax);
    attn_expsum_k<<<NE2 / 256, 256, 0, stream>>>(logits, dst2, segmax, denom, NE2);
    attn_scatter_k<<<NE2, 256, 0, stream>>>(xl, logits, denom, src2, dst2, x_nxt, 256, NE2);
    float* t = x_cur; x_cur = x_nxt; x_nxt = t;
  }

  // ---- fused decoder ----
  dec_fused_k<<<NE1 / 64, 256, 0, stream>>>(x_cur, e1, dec_W0, dec_b0, dec_W1, dec_b1,
                                            dec_W2, dec_b2, src1, dst1, out);
}

// Round 3
// 1849.729 us; speedup vs baseline: 3.2410x; 3.2410x over previous
//
#include <hip/hip_runtime.h>

#define Hd 256
#define NNODE 10000
#define NE1 131072
#define NE2 65536
#define ENC_CHUNK 16384

typedef __attribute__((ext_vector_type(8))) short bf16x8;
typedef __attribute__((ext_vector_type(4))) float f32x4;

#define MFMA16(a, b, c) __builtin_amdgcn_mfma_f32_16x16x32_bf16((a), (b), (c), 0, 0, 0)

__device__ __forceinline__ float b2f(ushort u) { return __uint_as_float(((unsigned)u) << 16); }
__device__ __forceinline__ ushort f2b(float f) {
  unsigned u = __float_as_uint(f);
  return (ushort)((u + 0x7fffu + ((u >> 16) & 1u)) >> 16);
}
__device__ __forceinline__ int fenc(float x) {
  int i = __float_as_int(x);
  return i >= 0 ? i : (i ^ 0x7fffffff);
}
__device__ __forceinline__ float fdec(int i) {
  return __int_as_float(i >= 0 ? i : (i ^ 0x7fffffff));
}

// ---------------- small kernels ----------------

__global__ void time_mlp_k(const float* __restrict__ tval,
                           const float* __restrict__ W0, const float* __restrict__ b0,
                           const float* __restrict__ W1, const float* __restrict__ b1,
                           const float* __restrict__ W2, const float* __restrict__ b2,
                           float* __restrict__ tenc) {
  __shared__ float h0[Hd], h1[Hd];
  int b = blockIdx.x, j = threadIdx.x;
  float t = tval[b];
  h0[j] = fmaxf(t * W0[j] + b0[j], 0.f);
  __syncthreads();
  float a = b1[j];
  for (int k = 0; k < Hd; ++k) a += h0[k] * W1[k * Hd + j];
  h1[j] = fmaxf(a, 0.f);
  __syncthreads();
  float c = b2[j];
  for (int k = 0; k < Hd; ++k) c += h1[k] * W2[k * Hd + j];
  tenc[b * Hd + j] = c;
}

__global__ void build_x0_k(const int* __restrict__ batch, const float* __restrict__ tenc,
                           float* __restrict__ x0) {
  int idx = blockIdx.x * 256 + threadIdx.x;
  int n = idx >> 9, j = idx & 511;
  x0[idx] = tenc[batch[n] * Hd + (j & 255)];
}

__global__ void enc_h0_k(const float* __restrict__ attr, const float* __restrict__ W0,
                         const float* __restrict__ b0, ushort* __restrict__ out) {
  int e = blockIdx.x, j = threadIdx.x;
  out[(size_t)e * Hd + j] = f2b(fmaxf(attr[e] * W0[j] + b0[j], 0.f));
}

__global__ void init_xnext_k(float* __restrict__ xn, const float* __restrict__ b1,
                             const float* __restrict__ b2) {
  int idx = blockIdx.x * 256 + threadIdx.x;
  int j = idx & 511;
  xn[idx] = (j < 256) ? b1[j] : b2[j - 256];
}

__global__ void init_seg_k(int* __restrict__ segmax, float* __restrict__ denom) {
  int i = blockIdx.x * 256 + threadIdx.x;
  if (i < NNODE) {
    segmax[i] = fenc(-__int_as_float(0x7f800000));
    denom[i] = 0.f;
  }
}

__global__ void f2b_k(const float* __restrict__ in, ushort* __restrict__ out, int n4) {
  int i = blockIdx.x * 256 + threadIdx.x;
  if (i < n4) {
    float4 v = ((const float4*)in)[i];
    ushort4 o;
    o.x = f2b(v.x); o.y = f2b(v.y); o.z = f2b(v.z); o.w = f2b(v.w);
    ((ushort4*)out)[i] = o;
  }
}

__global__ void cat512_k(const float* __restrict__ a, const float* __restrict__ b,
                         float* __restrict__ o) {
  int i = blockIdx.x * 256 + threadIdx.x;  // grid 2
  o[i] = (i < 256) ? a[i] : b[i - 256];
}

// transpose fp32 [K][256] -> bf16 out[(n_off+n)*ld_out + k]
__global__ void transpose_k(const float* __restrict__ in, ushort* __restrict__ out,
                            int K, int n_off, int ld_out) {
  __shared__ float t[32][33];
  int k0 = blockIdx.x * 32, n0 = blockIdx.y * 32;
  int tx = threadIdx.x & 31, ty = threadIdx.x >> 5;
#pragma unroll
  for (int p = 0; p < 4; ++p)
    t[ty + 8 * p][tx] = in[(size_t)(k0 + ty + 8 * p) * 256 + n0 + tx];
  __syncthreads();
#pragma unroll
  for (int p = 0; p < 4; ++p)
    out[(size_t)(n_off + n0 + ty + 8 * p) * ld_out + k0 + tx] = f2b(t[tx][ty + 8 * p]);
}

__global__ void attn_expsum_k(float* __restrict__ logits, const int* __restrict__ dst,
                              const int* __restrict__ segmax, float* __restrict__ denom, int E) {
  int e = blockIdx.x * 256 + threadIdx.x;
  if (e < E) {
    int d = dst[e];
    float ex = __expf(logits[e] - fdec(segmax[d]));
    logits[e] = ex;
    atomicAdd(denom + d, ex);
  }
}

// xl is bf16 rows of xlr (cols 0..255)
__global__ void attn_scatter_k(const ushort* __restrict__ xl, const float* __restrict__ ex,
                               const float* __restrict__ denom, const int* __restrict__ src,
                               const int* __restrict__ dst, float* __restrict__ xnext,
                               int colbase, int E) {
  int e = blockIdx.x, j = threadIdx.x;
  int s = src[e], d = dst[e];
  float alpha = ex[e] / (denom[d] + 1e-16f);
  atomicAdd(xnext + (size_t)d * 512 + colbase + j, b2f(xl[(size_t)s * 512 + j]) * alpha);
}

// ---------------- generic MFMA GEMM ----------------
// C[M, 256*gridDim.y] = op(A[M,K](bf16) @ W + bias), W given as WT[n][k] bf16.
// block: 256 thr = 4 waves; tile 64 rows x 256 cols (wave w -> cols w*64..+64).
template <bool RELU, bool OBF16>
__global__ __launch_bounds__(256, 2) void mgemm_k(
    const ushort* __restrict__ A, int lda, const ushort* __restrict__ WT, int K,
    const float* __restrict__ bias, void* __restrict__ C, int ldc, int M) {
  __shared__ ushort As[64][40];
  __shared__ ushort Bs[256][40];
  const int tid = threadIdx.x;
  const int wave = tid >> 6, lane = tid & 63;
  const int quad = lane >> 4, l15 = lane & 15;
  const int m0 = blockIdx.x * 64;
  const int ncol0 = blockIdx.y * 256;
  const ushort* WTb = WT + (size_t)ncol0 * K;
  const int arow = tid >> 2, akc = (tid & 3) << 3;
  int am = m0 + arow;
  if (am >= M) am = M - 1;
  f32x4 acc[4][4];
#pragma unroll
  for (int i = 0; i < 4; ++i)
#pragma unroll
    for (int j = 0; j < 4; ++j) acc[i][j] = (f32x4){0.f, 0.f, 0.f, 0.f};
  for (int k0 = 0; k0 < K; k0 += 32) {
    *(uint4*)&As[arow][akc] = *(const uint4*)(A + (size_t)am * lda + k0 + akc);
#pragma unroll
    for (int r = 0; r < 4; ++r) {
      int row = arow + r * 64;
      *(uint4*)&Bs[row][akc] = *(const uint4*)(WTb + (size_t)row * K + k0 + akc);
    }
    __syncthreads();
    bf16x8 bfr[4];
#pragma unroll
    for (int ni = 0; ni < 4; ++ni)
      bfr[ni] = *(const bf16x8*)&Bs[wave * 64 + ni * 16 + l15][quad * 8];
#pragma unroll
    for (int mi = 0; mi < 4; ++mi) {
      bf16x8 af = *(const bf16x8*)&As[mi * 16 + l15][quad * 8];
#pragma unroll
      for (int ni = 0; ni < 4; ++ni) acc[mi][ni] = MFMA16(af, bfr[ni], acc[mi][ni]);
    }
    __syncthreads();
  }
#pragma unroll
  for (int mi = 0; mi < 4; ++mi)
#pragma unroll
    for (int ni = 0; ni < 4; ++ni) {
      int c = ncol0 + wave * 64 + ni * 16 + l15;
      float bv = bias[c];
#pragma unroll
      for (int r = 0; r < 4; ++r) {
        int m = m0 + mi * 16 + quad * 4 + r;
        if (m < M) {
          float v = acc[mi][ni][r] + bv;
          if (RELU) v = fmaxf(v, 0.f);
          if (OBF16) ((ushort*)C)[(size_t)m * ldc + c] = f2b(v);
          else       ((float*)C)[(size_t)m * ldc + c] = v;
        }
      }
    }
}

// ---------------- fused MFMA attention logits ----------------
// logit_e = att . leakyrelu( xl[src] + xr[dst] + e@We ),  64 edges/block.
__global__ __launch_bounds__(256, 2) void attn_mfma_k(
    const ushort* __restrict__ eenc, const ushort* __restrict__ weT,
    const float* __restrict__ att, const ushort* __restrict__ xlr,
    const int* __restrict__ src, const int* __restrict__ dst,
    float* __restrict__ logits, int* __restrict__ segmax) {
  __shared__ ushort As[64][40];
  __shared__ ushort Bs[256][40];
  __shared__ ushort xs[64][264];
  __shared__ float red[4][64];
  __shared__ float att_s[256];
  const int tid = threadIdx.x;
  const int wave = tid >> 6, lane = tid & 63;
  const int quad = lane >> 4, l15 = lane & 15;
  const int m0 = blockIdx.x * 64;
  const int arow = tid >> 2, akc = (tid & 3) << 3;
  att_s[tid] = att[tid];
  {  // stage xs = bf16(xl[src] + xr[dst])
    int s = src[m0 + arow], d = dst[m0 + arow];
    int c0 = (tid & 3) * 64;
    const ushort* pl = xlr + (size_t)s * 512;
    const ushort* pr = xlr + (size_t)d * 512 + 256;
#pragma unroll
    for (int j = 0; j < 16; ++j) {
      int c = c0 + 4 * j;
      ushort4 a = *(const ushort4*)(pl + c);
      ushort4 b = *(const ushort4*)(pr + c);
      ushort4 o;
      o.x = f2b(b2f(a.x) + b2f(b.x)); o.y = f2b(b2f(a.y) + b2f(b.y));
      o.z = f2b(b2f(a.z) + b2f(b.z)); o.w = f2b(b2f(a.w) + b2f(b.w));
      *(ushort4*)&xs[arow][c] = o;
    }
  }
  f32x4 acc[4][4];
#pragma unroll
  for (int i = 0; i < 4; ++i)
#pragma unroll
    for (int j = 0; j < 4; ++j) acc[i][j] = (f32x4){0.f, 0.f, 0.f, 0.f};
  for (int k0 = 0; k0 < 256; k0 += 32) {
    *(uint4*)&As[arow][akc] = *(const uint4*)(eenc + (size_t)(m0 + arow) * 256 + k0 + akc);
#pragma unroll
    for (int r = 0; r < 4; ++r) {
      int row = arow + r * 64;
      *(uint4*)&Bs[row][akc] = *(const uint4*)(weT + (size_t)row * 256 + k0 + akc);
    }
    __syncthreads();
    bf16x8 bfr[4];
#pragma unroll
    for (int ni = 0; ni < 4; ++ni)
      bfr[ni] = *(const bf16x8*)&Bs[wave * 64 + ni * 16 + l15][quad * 8];
#pragma unroll
    for (int mi = 0; mi < 4; ++mi) {
      bf16x8 af = *(const bf16x8*)&As[mi * 16 + l15][quad * 8];
#pragma unroll
      for (int ni = 0; ni < 4; ++ni) acc[mi][ni] = MFMA16(af, bfr[ni], acc[mi][ni]);
    }
    __syncthreads();
  }
  float part[4][4];
#pragma unroll
  for (int mi = 0; mi < 4; ++mi)
#pragma unroll
    for (int r = 0; r < 4; ++r) part[mi][r] = 0.f;
#pragma unroll
  for (int mi = 0; mi < 4; ++mi)
#pragma unroll
    for (int ni = 0; ni < 4; ++ni) {
      int c = wave * 64 + ni * 16 + l15;
      float av = att_s[c];
#pragma unroll
      for (int r = 0; r < 4; ++r) {
        int row = mi * 16 + quad * 4 + r;
        float v = acc[mi][ni][r] + b2f(xs[row][c]);
        v = v > 0.f ? v : 0.2f * v;
        part[mi][r] += v * av;
      }
    }
#pragma unroll
  for (int d = 1; d < 16; d <<= 1)
#pragma unroll
    for (int mi = 0; mi < 4; ++mi)
#pragma unroll
      for (int r = 0; r < 4; ++r) part[mi][r] += __shfl_xor(part[mi][r], d);
  if (l15 == 0)
#pragma unroll
    for (int mi = 0; mi < 4; ++mi)
#pragma unroll
      for (int r = 0; r < 4; ++r) red[wave][mi * 16 + quad * 4 + r] = part[mi][r];
  __syncthreads();
  if (tid < 64) {
    float s = red[0][tid] + red[1][tid] + red[2][tid] + red[3][tid];
    int e = m0 + tid;
    logits[e] = s;
    atomicMax(segmax + dst[e], fenc(s));
  }
}

// ---------------- fused MFMA decoder ----------------
__global__ __launch_bounds__(256, 2) void dec_mfma_k(
    const ushort* __restrict__ xbf, const ushort* __restrict__ e1,
    const ushort* __restrict__ W0T, const float* __restrict__ b0,
    const ushort* __restrict__ W1T, const float* __restrict__ b1,
    const float* __restrict__ W2, const float* __restrict__ b2,
    const int* __restrict__ src, const int* __restrict__ dst,
    float* __restrict__ out) {
  __shared__ ushort As[64][40];
  __shared__ ushort Bs[256][40];
  __shared__ ushort h0[64][264];
  __shared__ float red[4][64];
  const int tid = threadIdx.x;
  const int wave = tid >> 6, lane = tid & 63;
  const int quad = lane >> 4, l15 = lane & 15;
  const int m0 = blockIdx.x * 64;
  const int arow = tid >> 2, akc = (tid & 3) << 3;
  const int gs = src[m0 + arow], gd = dst[m0 + arow];
  f32x4 acc[4][4];
#pragma unroll
  for (int i = 0; i < 4; ++i)
#pragma unroll
    for (int j = 0; j < 4; ++j) acc[i][j] = (f32x4){0.f, 0.f, 0.f, 0.f};
  // phase 1: h0 = relu([x_s | x_d | e1] @ W0 + b0), K=1280
  for (int k0 = 0; k0 < 1280; k0 += 32) {
    int k = k0 + akc;
    uint4 v;
    if (k < 512)       v = *(const uint4*)(xbf + (size_t)gs * 512 + k);
    else if (k < 1024) v = *(const uint4*)(xbf + (size_t)gd * 512 + (k - 512));
    else               v = *(const uint4*)(e1 + (size_t)(m0 + arow) * 256 + (k - 1024));
    *(uint4*)&As[arow][akc] = v;
#pragma unroll
    for (int r = 0; r < 4; ++r) {
      int row = arow + r * 64;
      *(uint4*)&Bs[row][akc] = *(const uint4*)(W0T + (size_t)row * 1280 + k0 + akc);
    }
    __syncthreads();
    bf16x8 bfr[4];
#pragma unroll
    for (int ni = 0; ni < 4; ++ni)
      bfr[ni] = *(const bf16x8*)&Bs[wave * 64 + ni * 16 + l15][quad * 8];
#pragma unroll
    for (int mi = 0; mi < 4; ++mi) {
      bf16x8 af = *(const bf16x8*)&As[mi * 16 + l15][quad * 8];
#pragma unroll
      for (int ni = 0; ni < 4; ++ni) acc[mi][ni] = MFMA16(af, bfr[ni], acc[mi][ni]);
    }
    __syncthreads();
  }
#pragma unroll
  for (int mi = 0; mi < 4; ++mi)
#pragma unroll
    for (int ni = 0; ni < 4; ++ni) {
      int c = wave * 64 + ni * 16 + l15;
      float bv = b0[c];
#pragma unroll
      for (int r = 0; r < 4; ++r)
        h0[mi * 16 + quad * 4 + r][c] = f2b(fmaxf(acc[mi][ni][r] + bv, 0.f));
    }
  __syncthreads();
  // phase 2: h1 = relu(h0 @ W1 + b1); out = h1 . W2 + b2
  f32x4 acc2[4][4];
#pragma unroll
  for (int i = 0; i < 4; ++i)
#pragma unroll
    for (int j = 0; j < 4; ++j) acc2[i][j] = (f32x4){0.f, 0.f, 0.f, 0.f};
  for (int k0 = 0; k0 < 256; k0 += 32) {
#pragma unroll
    for (int r = 0; r < 4; ++r) {
      int row = arow + r * 64;
      *(uint4*)&Bs[row][akc] = *(const uint4*)(W1T + (size_t)row * 256 + k0 + akc);
    }
    __syncthreads();
    bf16x8 bfr[4];
#pragma unroll
    for (int ni = 0; ni < 4; ++ni)
      bfr[ni] = *(const bf16x8*)&Bs[wave * 64 + ni * 16 + l15][quad * 8];
#pragma unroll
    for (int mi = 0; mi < 4; ++mi) {
      bf16x8 af = *(const bf16x8*)&h0[mi * 16 + l15][k0 + quad * 8];
#pragma unroll
      for (int ni = 0; ni < 4; ++ni) acc2[mi][ni] = MFMA16(af, bfr[ni], acc2[mi][ni]);
    }
    __syncthreads();
  }
  float part[4][4];
#pragma unroll
  for (int mi = 0; mi < 4; ++mi)
#pragma unroll
    for (int r = 0; r < 4; ++r) part[mi][r] = 0.f;
#pragma unroll
  for (int mi = 0; mi < 4; ++mi)
#pragma unroll
    for (int ni = 0; ni < 4; ++ni) {
      int c = wave * 64 + ni * 16 + l15;
      float bv = b1[c], wv = W2[c];
#pragma unroll
      for (int r = 0; r < 4; ++r) {
        float v = fmaxf(acc2[mi][ni][r] + bv, 0.f);
        part[mi][r] += v * wv;
      }
    }
#pragma unroll
  for (int d = 1; d < 16; d <<= 1)
#pragma unroll
    for (int mi = 0; mi < 4; ++mi)
#pragma unroll
      for (int r = 0; r < 4; ++r) part[mi][r] += __shfl_xor(part[mi][r], d);
  if (l15 == 0)
#pragma unroll
    for (int mi = 0; mi < 4; ++mi)
#pragma unroll
      for (int r = 0; r < 4; ++r) red[wave][mi * 16 + quad * 4 + r] = part[mi][r];
  __syncthreads();
  if (tid < 64) {
    float s = red[0][tid] + red[1][tid] + red[2][tid] + red[3][tid];
    out[m0 + tid] = s + b2[0];
  }
}

// ---------------- host ----------------

extern "C" void kernel_launch(void* const* d_in, const int* in_sizes, int n_in,
                              void* d_out, int out_size, void* d_ws, size_t ws_size,
                              hipStream_t stream) {
  const int*   eidx1  = (const int*)d_in[0];
  const float* eattr1 = (const float*)d_in[1];
  const int*   eidx2  = (const int*)d_in[2];
  const float* eattr2 = (const float*)d_in[3];
  const int*   batch  = (const int*)d_in[4];
  const float* tval   = (const float*)d_in[5];
  const float* te_W0 = (const float*)d_in[6];
  const float* te_b0 = (const float*)d_in[7];
  const float* te_W1 = (const float*)d_in[8];
  const float* te_b1 = (const float*)d_in[9];
  const float* te_W2 = (const float*)d_in[10];
  const float* te_b2 = (const float*)d_in[11];
  const float* ee_W0 = (const float*)d_in[12];
  const float* ee_b0 = (const float*)d_in[13];
  const float* ee_W1 = (const float*)d_in[14];
  const float* ee_b1 = (const float*)d_in[15];
  const float* ee_W2 = (const float*)d_in[16];
  const float* ee_b2 = (const float*)d_in[17];
  const float* dec_W0 = (const float*)d_in[18];
  const float* dec_b0 = (const float*)d_in[19];
  const float* dec_W1 = (const float*)d_in[20];
  const float* dec_b1 = (const float*)d_in[21];
  const float* dec_W2 = (const float*)d_in[22];
  const float* dec_b2 = (const float*)d_in[23];
  const float* gg_Wl  = (const float*)d_in[24];
  const float* gg_bl  = (const float*)d_in[25];
  const float* gg_Wr  = (const float*)d_in[26];
  const float* gg_br  = (const float*)d_in[27];
  const float* gg_We  = (const float*)d_in[28];
  const float* gg_att = (const float*)d_in[29];
  const float* gg_bias= (const float*)d_in[30];
  const float* gf_Wl  = (const float*)d_in[31];
  const float* gf_bl  = (const float*)d_in[32];
  const float* gf_Wr  = (const float*)d_in[33];
  const float* gf_br  = (const float*)d_in[34];
  const float* gf_We  = (const float*)d_in[35];
  const float* gf_att = (const float*)d_in[36];
  const float* gf_bias= (const float*)d_in[37];
  (void)in_sizes; (void)n_in; (void)out_size; (void)ws_size;

  const int* src1 = eidx1;
  const int* dst1 = eidx1 + NE1;
  const int* src2 = eidx2;
  const int* dst2 = eidx2 + NE2;

  char* base = (char*)d_ws;
  size_t off = 0;
  auto alloc = [&](size_t bytes) {
    void* p = base + off;
    off += (bytes + 255) & ~(size_t)255;
    return p;
  };
  float*  x_cur  = (float*)alloc((size_t)NNODE * 512 * 4);
  float*  x_nxt  = (float*)alloc((size_t)NNODE * 512 * 4);
  ushort* x_bf   = (ushort*)alloc((size_t)NNODE * 512 * 2);
  ushort* xlr    = (ushort*)alloc((size_t)NNODE * 512 * 2);
  ushort* e1     = (ushort*)alloc((size_t)NE1 * Hd * 2);
  ushort* e2     = (ushort*)alloc((size_t)NE2 * Hd * 2);
  float*  logits = (float*)alloc((size_t)NE1 * 4);
  float*  denom  = (float*)alloc((size_t)NNODE * 4);
  int*    segmax = (int*)alloc((size_t)NNODE * 4);
  float*  tenc   = (float*)alloc((size_t)16 * Hd * 4);
  ushort* eeW1T  = (ushort*)alloc((size_t)256 * 256 * 2);
  ushort* eeW2T  = (ushort*)alloc((size_t)256 * 256 * 2);
  ushort* decW0T = (ushort*)alloc((size_t)256 * 1280 * 2);
  ushort* decW1T = (ushort*)alloc((size_t)256 * 256 * 2);
  ushort* wlrT   = (ushort*)alloc((size_t)6 * 512 * 512 * 2);  // [g*3+i]
  ushort* weT    = (ushort*)alloc((size_t)6 * 256 * 256 * 2);
  float*  biascat= (float*)alloc((size_t)6 * 512 * 4);

  float* out = (float*)d_out;

  // ---- weight prep ----
  transpose_k<<<dim3(8, 8), 256, 0, stream>>>(ee_W1, eeW1T, 256, 0, 256);
  transpose_k<<<dim3(8, 8), 256, 0, stream>>>(ee_W2, eeW2T, 256, 0, 256);
  transpose_k<<<dim3(40, 8), 256, 0, stream>>>(dec_W0, decW0T, 1280, 0, 1280);
  transpose_k<<<dim3(8, 8), 256, 0, stream>>>(dec_W1, decW1T, 256, 0, 256);
  for (int i = 0; i < 3; ++i) {
    transpose_k<<<dim3(16, 8), 256, 0, stream>>>(gg_Wl + (size_t)i * 512 * 256, wlrT + (size_t)i * 512 * 512, 512, 0, 512);
    transpose_k<<<dim3(16, 8), 256, 0, stream>>>(gg_Wr + (size_t)i * 512 * 256, wlrT + (size_t)i * 512 * 512, 512, 256, 512);
    transpose_k<<<dim3(16, 8), 256, 0, stream>>>(gf_Wl + (size_t)i * 512 * 256, wlrT + (size_t)(3 + i) * 512 * 512, 512, 0, 512);
    transpose_k<<<dim3(16, 8), 256, 0, stream>>>(gf_Wr + (size_t)i * 512 * 256, wlrT + (size_t)(3 + i) * 512 * 512, 512, 256, 512);
    transpose_k<<<dim3(8, 8), 256, 0, stream>>>(gg_We + (size_t)i * 256 * 256, weT + (size_t)i * 256 * 256, 256, 0, 256);
    transpose_k<<<dim3(8, 8), 256, 0, stream>>>(gf_We + (size_t)i * 256 * 256, weT + (size_t)(3 + i) * 256 * 256, 256, 0, 256);
    cat512_k<<<2, 256, 0, stream>>>(gg_bl + i * 256, gg_br + i * 256, biascat + i * 512);
    cat512_k<<<2, 256, 0, stream>>>(gf_bl + i * 256, gf_br + i * 256, biascat + (3 + i) * 512);
  }

  // ---- edge encoder (chunked; x_cur/x_nxt as bf16 scratch, not yet live) ----
  ushort* h0b = (ushort*)x_cur;
  ushort* h1b = (ushort*)x_nxt;
  for (int c = 0; c < NE1 / ENC_CHUNK; ++c) {
    enc_h0_k<<<ENC_CHUNK, 256, 0, stream>>>(eattr1 + (size_t)c * ENC_CHUNK, ee_W0, ee_b0, h0b);
    mgemm_k<true, true><<<dim3(ENC_CHUNK / 64, 1), 256, 0, stream>>>(h0b, 256, eeW1T, 256, ee_b1, h1b, 256, ENC_CHUNK);
    mgemm_k<false, true><<<dim3(ENC_CHUNK / 64, 1), 256, 0, stream>>>(h1b, 256, eeW2T, 256, ee_b2, e1 + (size_t)c * ENC_CHUNK * Hd, 256, ENC_CHUNK);
  }
  for (int c = 0; c < NE2 / ENC_CHUNK; ++c) {
    enc_h0_k<<<ENC_CHUNK, 256, 0, stream>>>(eattr2 + (size_t)c * ENC_CHUNK, ee_W0, ee_b0, h0b);
    mgemm_k<true, true><<<dim3(ENC_CHUNK / 64, 1), 256, 0, stream>>>(h0b, 256, eeW1T, 256, ee_b1, h1b, 256, ENC_CHUNK);
    mgemm_k<false, true><<<dim3(ENC_CHUNK / 64, 1), 256, 0, stream>>>(h1b, 256, eeW2T, 256, ee_b2, e2 + (size_t)c * ENC_CHUNK * Hd, 256, ENC_CHUNK);
  }

  // ---- time encoding -> x0 ----
  time_mlp_k<<<16, 256, 0, stream>>>(tval, te_W0, te_b0, te_W1, te_b1, te_W2, te_b2, tenc);
  build_x0_k<<<(NNODE * 512) / 256, 256, 0, stream>>>(batch, tenc, x_cur);

  const int ngrid = (NNODE + 63) / 64;
  for (int i = 0; i < 3; ++i) {
    f2b_k<<<(NNODE * 512 / 4 + 255) / 256, 256, 0, stream>>>(x_cur, x_bf, NNODE * 512 / 4);
    init_xnext_k<<<(NNODE * 512) / 256, 256, 0, stream>>>(x_nxt, gg_bias + i * Hd, gf_bias + i * Hd);
    // ---- graph 1 ----
    mgemm_k<false, true><<<dim3(ngrid, 2), 256, 0, stream>>>(x_bf, 512, wlrT + (size_t)i * 512 * 512, 512, biascat + i * 512, xlr, 512, NNODE);
    init_seg_k<<<(NNODE + 255) / 256, 256, 0, stream>>>(segmax, denom);
    attn_mfma_k<<<NE1 / 64, 256, 0, stream>>>(e1, weT + (size_t)i * 256 * 256, gg_att + i * Hd, xlr, src1, dst1, logits, segmax);
    attn_expsum_k<<<NE1 / 256, 256, 0, stream>>>(logits, dst1, segmax, denom, NE1);
    attn_scatter_k<<<NE1, 256, 0, stream>>>(xlr, logits, denom, src1, dst1, x_nxt, 0, NE1);
    // ---- graph 2 ----
    mgemm_k<false, true><<<dim3(ngrid, 2), 256, 0, stream>>>(x_bf, 512, wlrT + (size_t)(3 + i) * 512 * 512, 512, biascat + (3 + i) * 512, xlr, 512, NNODE);
    init_seg_k<<<(NNODE + 255) / 256, 256, 0, stream>>>(segmax, denom);
    attn_mfma_k<<<NE2 / 64, 256, 0, stream>>>(e2, weT + (size_t)(3 + i) * 256 * 256, gf_att + i * Hd, xlr, src2, dst2, logits, segmax);
    attn_expsum_k<<<NE2 / 256, 256, 0, stream>>>(logits, dst2, segmax, denom, NE2);
    attn_scatter_k<<<NE2, 256, 0, stream>>>(xlr, logits, denom, src2, dst2, x_nxt, 256, NE2);
    float* t = x_cur; x_cur = x_nxt; x_nxt = t;
  }

  // ---- decoder ----
  f2b_k<<<(NNODE * 512 / 4 + 255) / 256, 256, 0, stream>>>(x_cur, x_bf, NNODE * 512 / 4);
  dec_mfma_k<<<NE1 / 64, 256, 0, stream>>>(x_bf, e1, decW0T, dec_b0, decW1T, dec_b1,
                                           dec_W2, dec_b2, src1, dst1, out);
}

// Round 4
// 1123.931 us; speedup vs baseline: 5.3339x; 1.6458x over previous
//
#include <hip/hip_runtime.h>

#define Hd 256
#define NNODE 10000
#define NE1 131072
#define NE2 65536

typedef __attribute__((ext_vector_type(8))) short bf16x8;
typedef __attribute__((ext_vector_type(4))) float f32x4;

#define MFMA16(a, b, c) __builtin_amdgcn_mfma_f32_16x16x32_bf16((a), (b), (c), 0, 0, 0)

__device__ __forceinline__ float b2f(ushort u) { return __uint_as_float(((unsigned)u) << 16); }
__device__ __forceinline__ ushort f2b(float f) {
  unsigned u = __float_as_uint(f);
  return (ushort)((u + 0x7fffu + ((u >> 16) & 1u)) >> 16);
}

// ---------------- small kernels ----------------

__global__ void time_mlp_k(const float* __restrict__ tval,
                           const float* __restrict__ W0, const float* __restrict__ b0,
                           const float* __restrict__ W1, const float* __restrict__ b1,
                           const float* __restrict__ W2, const float* __restrict__ b2,
                           float* __restrict__ tenc) {
  __shared__ float h0[Hd], h1[Hd];
  int b = blockIdx.x, j = threadIdx.x;
  float t = tval[b];
  h0[j] = fmaxf(t * W0[j] + b0[j], 0.f);
  __syncthreads();
  float a = b1[j];
  for (int k = 0; k < Hd; ++k) a += h0[k] * W1[k * Hd + j];
  h1[j] = fmaxf(a, 0.f);
  __syncthreads();
  float c = b2[j];
  for (int k = 0; k < Hd; ++k) c += h1[k] * W2[k * Hd + j];
  tenc[b * Hd + j] = c;
}

// x0 (bf16) [n][j] = tenc[batch[n]][j & 255], j in [0,512)
__global__ void build_x0_k(const int* __restrict__ batch, const float* __restrict__ tenc,
                           ushort* __restrict__ x0) {
  int idx = blockIdx.x * 256 + threadIdx.x;
  int n = idx >> 9;
  x0[idx] = f2b(tenc[batch[n] * Hd + (idx & 255)]);
}

__global__ void cat512_k(const float* __restrict__ a, const float* __restrict__ b,
                         float* __restrict__ o) {
  int i = blockIdx.x * 256 + threadIdx.x;  // grid 2
  o[i] = (i < 256) ? a[i] : b[i - 256];
}

// transpose fp32 [K][256] -> bf16 out[(n_off+n)*ld_out + k]
__global__ void transpose_k(const float* __restrict__ in, ushort* __restrict__ out,
                            int K, int n_off, int ld_out) {
  __shared__ float t[32][33];
  int k0 = blockIdx.x * 32, n0 = blockIdx.y * 32;
  int tx = threadIdx.x & 31, ty = threadIdx.x >> 5;
#pragma unroll
  for (int p = 0; p < 4; ++p)
    t[ty + 8 * p][tx] = in[(size_t)(k0 + ty + 8 * p) * 256 + n0 + tx];
  __syncthreads();
#pragma unroll
  for (int p = 0; p < 4; ++p)
    out[(size_t)(n_off + n0 + ty + 8 * p) * ld_out + k0 + tx] = f2b(t[tx][ty + 8 * p]);
}

// ---------------- CSR build (by dst) ----------------

__global__ void zero_k(int* __restrict__ p, int n) {
  int i = blockIdx.x * 256 + threadIdx.x;
  if (i < n) p[i] = 0;
}

__global__ void deg_k(const int* __restrict__ dst, int* __restrict__ cnt, int E) {
  int e = blockIdx.x * 256 + threadIdx.x;
  if (e < E) atomicAdd(cnt + dst[e], 1);
}

// single block, 640 threads; 625 x 16 = 10000 bins
__global__ void scan_k(const int* __restrict__ cnt, int* __restrict__ rowstart, int E) {
  __shared__ int part[626];
  int t = threadIdx.x;
  if (t < 625) {
    int s = 0;
#pragma unroll
    for (int i = 0; i < 16; ++i) s += cnt[t * 16 + i];
    part[t] = s;
  }
  __syncthreads();
  if (t == 0) {
    int run = 0;
    for (int i = 0; i < 625; ++i) { int v = part[i]; part[i] = run; run += v; }
  }
  __syncthreads();
  if (t < 625) {
    int off = part[t];
#pragma unroll
    for (int i = 0; i < 16; ++i) { rowstart[t * 16 + i] = off; off += cnt[t * 16 + i]; }
  }
  if (t == 0) rowstart[NNODE] = E;
}

__global__ void fill_k(const int* __restrict__ dst, const int* __restrict__ rowstart,
                       int* __restrict__ cur, int* __restrict__ eid, int E) {
  int e = blockIdx.x * 256 + threadIdx.x;
  if (e < E) {
    int d = dst[e];
    int idx = rowstart[d] + atomicAdd(cur + d, 1);
    eid[idx] = e;
  }
}

// ---------------- fused softmax + aggregate (one wave per node) ----------------
// xnext[n][colbase + c] = bias[c] + sum_e alpha_e * xl[src[e]][c]
__global__ __launch_bounds__(256) void aggregate_k(
    const float* __restrict__ logits, const ushort* __restrict__ xlr,
    const int* __restrict__ src, const int* __restrict__ rowstart,
    const int* __restrict__ eid, const float* __restrict__ bias,
    ushort* __restrict__ xnext, int colbase) {
  const int tid = threadIdx.x;
  const int wave = tid >> 6, lane = tid & 63;
  const int nid = blockIdx.x * 4 + wave;
  if (nid >= NNODE) return;
  const int s0 = rowstart[nid], s1 = rowstart[nid + 1];
  float mx = -__int_as_float(0x7f800000);
  for (int i = s0 + lane; i < s1; i += 64) mx = fmaxf(mx, logits[eid[i]]);
#pragma unroll
  for (int d = 1; d < 64; d <<= 1) mx = fmaxf(mx, __shfl_xor(mx, d));
  float den = 0.f;
  for (int i = s0 + lane; i < s1; i += 64) den += __expf(logits[eid[i]] - mx);
#pragma unroll
  for (int d = 1; d < 64; d <<= 1) den += __shfl_xor(den, d);
  float acc0 = 0.f, acc1 = 0.f, acc2 = 0.f, acc3 = 0.f;
  for (int i = s0; i < s1; ++i) {
    int e = eid[i];
    float w = __expf(logits[e] - mx);  // uniform across wave (broadcast loads)
    int s = src[e];
    ushort4 v = *(const ushort4*)(xlr + (size_t)s * 512 + lane * 4);
    acc0 += w * b2f(v.x); acc1 += w * b2f(v.y);
    acc2 += w * b2f(v.z); acc3 += w * b2f(v.w);
  }
  float inv = 1.f / (den + 1e-16f);
  int c = lane * 4;
  ushort4 o;
  o.x = f2b(acc0 * inv + bias[c + 0]);
  o.y = f2b(acc1 * inv + bias[c + 1]);
  o.z = f2b(acc2 * inv + bias[c + 2]);
  o.w = f2b(acc3 * inv + bias[c + 3]);
  *(ushort4*)(xnext + (size_t)nid * 512 + colbase + c) = o;
}

// ---------------- generic MFMA GEMM ----------------
// C[M, 256*gridDim.y] = op(A[M,K](bf16) @ W + bias), W given as WT[n][k] bf16.
template <bool RELU, bool OBF16>
__global__ __launch_bounds__(256, 2) void mgemm_k(
    const ushort* __restrict__ A, int lda, const ushort* __restrict__ WT, int K,
    const float* __restrict__ bias, void* __restrict__ C, int ldc, int M) {
  __shared__ ushort As[64][40];
  __shared__ ushort Bs[256][40];
  const int tid = threadIdx.x;
  const int wave = tid >> 6, lane = tid & 63;
  const int quad = lane >> 4, l15 = lane & 15;
  const int m0 = blockIdx.x * 64;
  const int ncol0 = blockIdx.y * 256;
  const ushort* WTb = WT + (size_t)ncol0 * K;
  const int arow = tid >> 2, akc = (tid & 3) << 3;
  int am = m0 + arow;
  if (am >= M) am = M - 1;
  f32x4 acc[4][4];
#pragma unroll
  for (int i = 0; i < 4; ++i)
#pragma unroll
    for (int j = 0; j < 4; ++j) acc[i][j] = (f32x4){0.f, 0.f, 0.f, 0.f};
  for (int k0 = 0; k0 < K; k0 += 32) {
    *(uint4*)&As[arow][akc] = *(const uint4*)(A + (size_t)am * lda + k0 + akc);
#pragma unroll
    for (int r = 0; r < 4; ++r) {
      int row = arow + r * 64;
      *(uint4*)&Bs[row][akc] = *(const uint4*)(WTb + (size_t)row * K + k0 + akc);
    }
    __syncthreads();
    bf16x8 bfr[4];
#pragma unroll
    for (int ni = 0; ni < 4; ++ni)
      bfr[ni] = *(const bf16x8*)&Bs[wave * 64 + ni * 16 + l15][quad * 8];
#pragma unroll
    for (int mi = 0; mi < 4; ++mi) {
      bf16x8 af = *(const bf16x8*)&As[mi * 16 + l15][quad * 8];
#pragma unroll
      for (int ni = 0; ni < 4; ++ni) acc[mi][ni] = MFMA16(af, bfr[ni], acc[mi][ni]);
    }
    __syncthreads();
  }
#pragma unroll
  for (int mi = 0; mi < 4; ++mi)
#pragma unroll
    for (int ni = 0; ni < 4; ++ni) {
      int c = ncol0 + wave * 64 + ni * 16 + l15;
      float bv = bias[c];
#pragma unroll
      for (int r = 0; r < 4; ++r) {
        int m = m0 + mi * 16 + quad * 4 + r;
        if (m < M) {
          float v = acc[mi][ni][r] + bv;
          if (RELU) v = fmaxf(v, 0.f);
          if (OBF16) ((ushort*)C)[(size_t)m * ldc + c] = f2b(v);
          else       ((float*)C)[(size_t)m * ldc + c] = v;
        }
      }
    }
}

// ---------------- fused edge-encoder MLP (64 edges / block) ----------------
// e_out = (relu(relu(attr*W0+b0) @ W1 + b1)) @ W2 + b2   (bf16 out)
__global__ __launch_bounds__(256, 2) void enc_fused_k(
    const float* __restrict__ attr, const float* __restrict__ W0,
    const float* __restrict__ b0, const ushort* __restrict__ W1T,
    const float* __restrict__ b1, const ushort* __restrict__ W2T,
    const float* __restrict__ b2, ushort* __restrict__ eout) {
  __shared__ ushort h[64][264];
  __shared__ ushort Bs[256][40];
  __shared__ float w0s[256], b0s[256];
  const int tid = threadIdx.x;
  const int wave = tid >> 6, lane = tid & 63;
  const int quad = lane >> 4, l15 = lane & 15;
  const int m0 = blockIdx.x * 64;
  const int arow = tid >> 2, akc = (tid & 3) << 3;
  w0s[tid] = W0[tid];
  b0s[tid] = b0[tid];
  float a0 = attr[m0 + arow];
  __syncthreads();
  {
    int c0 = (tid & 3) * 64;
#pragma unroll
    for (int j = 0; j < 64; j += 4) {
      int c = c0 + j;
      ushort4 o;
      o.x = f2b(fmaxf(a0 * w0s[c + 0] + b0s[c + 0], 0.f));
      o.y = f2b(fmaxf(a0 * w0s[c + 1] + b0s[c + 1], 0.f));
      o.z = f2b(fmaxf(a0 * w0s[c + 2] + b0s[c + 2], 0.f));
      o.w = f2b(fmaxf(a0 * w0s[c + 3] + b0s[c + 3], 0.f));
      *(ushort4*)&h[arow][c] = o;
    }
  }
  __syncthreads();
  // phase A: h1 = relu(h @ W1 + b1)
  f32x4 acc[4][4];
#pragma unroll
  for (int i = 0; i < 4; ++i)
#pragma unroll
    for (int j = 0; j < 4; ++j) acc[i][j] = (f32x4){0.f, 0.f, 0.f, 0.f};
  for (int k0 = 0; k0 < 256; k0 += 32) {
#pragma unroll
    for (int r = 0; r < 4; ++r) {
      int row = arow + r * 64;
      *(uint4*)&Bs[row][akc] = *(const uint4*)(W1T + (size_t)row * 256 + k0 + akc);
    }
    __syncthreads();
    bf16x8 bfr[4];
#pragma unroll
    for (int ni = 0; ni < 4; ++ni)
      bfr[ni] = *(const bf16x8*)&Bs[wave * 64 + ni * 16 + l15][quad * 8];
#pragma unroll
    for (int mi = 0; mi < 4; ++mi) {
      bf16x8 af = *(const bf16x8*)&h[mi * 16 + l15][k0 + quad * 8];
#pragma unroll
      for (int ni = 0; ni < 4; ++ni) acc[mi][ni] = MFMA16(af, bfr[ni], acc[mi][ni]);
    }
    __syncthreads();
  }
#pragma unroll
  for (int mi = 0; mi < 4; ++mi)
#pragma unroll
    for (int ni = 0; ni < 4; ++ni) {
      int c = wave * 64 + ni * 16 + l15;
      float bv = b1[c];
#pragma unroll
      for (int r = 0; r < 4; ++r)
        h[mi * 16 + quad * 4 + r][c] = f2b(fmaxf(acc[mi][ni][r] + bv, 0.f));
    }
  __syncthreads();
  // phase B: eout = h1 @ W2 + b2
  f32x4 acc2[4][4];
#pragma unroll
  for (int i = 0; i < 4; ++i)
#pragma unroll
    for (int j = 0; j < 4; ++j) acc2[i][j] = (f32x4){0.f, 0.f, 0.f, 0.f};
  for (int k0 = 0; k0 < 256; k0 += 32) {
#pragma unroll
    for (int r = 0; r < 4; ++r) {
      int row = arow + r * 64;
      *(uint4*)&Bs[row][akc] = *(const uint4*)(W2T + (size_t)row * 256 + k0 + akc);
    }
    __syncthreads();
    bf16x8 bfr[4];
#pragma unroll
    for (int ni = 0; ni < 4; ++ni)
      bfr[ni] = *(const bf16x8*)&Bs[wave * 64 + ni * 16 + l15][quad * 8];
#pragma unroll
    for (int mi = 0; mi < 4; ++mi) {
      bf16x8 af = *(const bf16x8*)&h[mi * 16 + l15][k0 + quad * 8];
#pragma unroll
      for (int ni = 0; ni < 4; ++ni) acc2[mi][ni] = MFMA16(af, bfr[ni], acc2[mi][ni]);
    }
    __syncthreads();
  }
#pragma unroll
  for (int mi = 0; mi < 4; ++mi)
#pragma unroll
    for (int ni = 0; ni < 4; ++ni) {
      int c = wave * 64 + ni * 16 + l15;
      float bv = b2[c];
#pragma unroll
      for (int r = 0; r < 4; ++r) {
        int m = m0 + mi * 16 + quad * 4 + r;
        eout[(size_t)m * 256 + c] = f2b(acc2[mi][ni][r] + bv);
      }
    }
}

// ---------------- fused MFMA attention logits ----------------
// logit_e = att . leakyrelu( xl[src] + xr[dst] + e@We ),  64 edges/block.
__global__ __launch_bounds__(256, 2) void attn_mfma_k(
    const ushort* __restrict__ eenc, const ushort* __restrict__ weT,
    const float* __restrict__ att, const ushort* __restrict__ xlr,
    const int* __restrict__ src, const int* __restrict__ dst,
    float* __restrict__ logits) {
  __shared__ ushort As[64][40];
  __shared__ ushort Bs[256][40];
  __shared__ ushort xs[64][264];
  __shared__ float red[4][64];
  __shared__ float att_s[256];
  const int tid = threadIdx.x;
  const int wave = tid >> 6, lane = tid & 63;
  const int quad = lane >> 4, l15 = lane & 15;
  const int m0 = blockIdx.x * 64;
  const int arow = tid >> 2, akc = (tid & 3) << 3;
  att_s[tid] = att[tid];
  {  // stage xs = bf16(xl[src] + xr[dst])
    int s = src[m0 + arow], d = dst[m0 + arow];
    int c0 = (tid & 3) * 64;
    const ushort* pl = xlr + (size_t)s * 512;
    const ushort* pr = xlr + (size_t)d * 512 + 256;
#pragma unroll
    for (int j = 0; j < 16; ++j) {
      int c = c0 + 4 * j;
      ushort4 a = *(const ushort4*)(pl + c);
      ushort4 b = *(const ushort4*)(pr + c);
      ushort4 o;
      o.x = f2b(b2f(a.x) + b2f(b.x)); o.y = f2b(b2f(a.y) + b2f(b.y));
      o.z = f2b(b2f(a.z) + b2f(b.z)); o.w = f2b(b2f(a.w) + b2f(b.w));
      *(ushort4*)&xs[arow][c] = o;
    }
  }
  f32x4 acc[4][4];
#pragma unroll
  for (int i = 0; i < 4; ++i)
#pragma unroll
    for (int j = 0; j < 4; ++j) acc[i][j] = (f32x4){0.f, 0.f, 0.f, 0.f};
  for (int k0 = 0; k0 < 256; k0 += 32) {
    *(uint4*)&As[arow][akc] = *(const uint4*)(eenc + (size_t)(m0 + arow) * 256 + k0 + akc);
#pragma unroll
    for (int r = 0; r < 4; ++r) {
      int row = arow + r * 64;
      *(uint4*)&Bs[row][akc] = *(const uint4*)(weT + (size_t)row * 256 + k0 + akc);
    }
    __syncthreads();
    bf16x8 bfr[4];
#pragma unroll
    for (int ni = 0; ni < 4; ++ni)
      bfr[ni] = *(const bf16x8*)&Bs[wave * 64 + ni * 16 + l15][quad * 8];
#pragma unroll
    for (int mi = 0; mi < 4; ++mi) {
      bf16x8 af = *(const bf16x8*)&As[mi * 16 + l15][quad * 8];
#pragma unroll
      for (int ni = 0; ni < 4; ++ni) acc[mi][ni] = MFMA16(af, bfr[ni], acc[mi][ni]);
    }
    __syncthreads();
  }
  float part[4][4];
#pragma unroll
  for (int mi = 0; mi < 4; ++mi)
#pragma unroll
    for (int r = 0; r < 4; ++r) part[mi][r] = 0.f;
#pragma unroll
  for (int mi = 0; mi < 4; ++mi)
#pragma unroll
    for (int ni = 0; ni < 4; ++ni) {
      int c = wave * 64 + ni * 16 + l15;
      float av = att_s[c];
#pragma unroll
      for (int r = 0; r < 4; ++r) {
        int row = mi * 16 + quad * 4 + r;
        float v = acc[mi][ni][r] + b2f(xs[row][c]);
        v = v > 0.f ? v : 0.2f * v;
        part[mi][r] += v * av;
      }
    }
#pragma unroll
  for (int d = 1; d < 16; d <<= 1)
#pragma unroll
    for (int mi = 0; mi < 4; ++mi)
#pragma unroll
      for (int r = 0; r < 4; ++r) part[mi][r] += __shfl_xor(part[mi][r], d);
  if (l15 == 0)
#pragma unroll
    for (int mi = 0; mi < 4; ++mi)
#pragma unroll
      for (int r = 0; r < 4; ++r) red[wave][mi * 16 + quad * 4 + r] = part[mi][r];
  __syncthreads();
  if (tid < 64)
    logits[m0 + tid] = red[0][tid] + red[1][tid] + red[2][tid] + red[3][tid];
}

// ---------------- fused MFMA decoder ----------------
__global__ __launch_bounds__(256, 2) void dec_mfma_k(
    const ushort* __restrict__ xbf, const ushort* __restrict__ e1,
    const ushort* __restrict__ W0T, const float* __restrict__ b0,
    const ushort* __restrict__ W1T, const float* __restrict__ b1,
    const float* __restrict__ W2, const float* __restrict__ b2,
    const int* __restrict__ src, const int* __restrict__ dst,
    float* __restrict__ out) {
  __shared__ ushort As[64][40];
  __shared__ ushort Bs[256][40];
  __shared__ ushort h0[64][264];
  __shared__ float red[4][64];
  const int tid = threadIdx.x;
  const int wave = tid >> 6, lane = tid & 63;
  const int quad = lane >> 4, l15 = lane & 15;
  const int m0 = blockIdx.x * 64;
  const int arow = tid >> 2, akc = (tid & 3) << 3;
  const int gs = src[m0 + arow], gd = dst[m0 + arow];
  f32x4 acc[4][4];
#pragma unroll
  for (int i = 0; i < 4; ++i)
#pragma unroll
    for (int j = 0; j < 4; ++j) acc[i][j] = (f32x4){0.f, 0.f, 0.f, 0.f};
  for (int k0 = 0; k0 < 1280; k0 += 32) {
    int k = k0 + akc;
    uint4 v;
    if (k < 512)       v = *(const uint4*)(xbf + (size_t)gs * 512 + k);
    else if (k < 1024) v = *(const uint4*)(xbf + (size_t)gd * 512 + (k - 512));
    else               v = *(const uint4*)(e1 + (size_t)(m0 + arow) * 256 + (k - 1024));
    *(uint4*)&As[arow][akc] = v;
#pragma unroll
    for (int r = 0; r < 4; ++r) {
      int row = arow + r * 64;
      *(uint4*)&Bs[row][akc] = *(const uint4*)(W0T + (size_t)row * 1280 + k0 + akc);
    }
    __syncthreads();
    bf16x8 bfr[4];
#pragma unroll
    for (int ni = 0; ni < 4; ++ni)
      bfr[ni] = *(const bf16x8*)&Bs[wave * 64 + ni * 16 + l15][quad * 8];
#pragma unroll
    for (int mi = 0; mi < 4; ++mi) {
      bf16x8 af = *(const bf16x8*)&As[mi * 16 + l15][quad * 8];
#pragma unroll
      for (int ni = 0; ni < 4; ++ni) acc[mi][ni] = MFMA16(af, bfr[ni], acc[mi][ni]);
    }
    __syncthreads();
  }
#pragma unroll
  for (int mi = 0; mi < 4; ++mi)
#pragma unroll
    for (int ni = 0; ni < 4; ++ni) {
      int c = wave * 64 + ni * 16 + l15;
      float bv = b0[c];
#pragma unroll
      for (int r = 0; r < 4; ++r)
        h0[mi * 16 + quad * 4 + r][c] = f2b(fmaxf(acc[mi][ni][r] + bv, 0.f));
    }
  __syncthreads();
  f32x4 acc2[4][4];
#pragma unroll
  for (int i = 0; i < 4; ++i)
#pragma unroll
    for (int j = 0; j < 4; ++j) acc2[i][j] = (f32x4){0.f, 0.f, 0.f, 0.f};
  for (int k0 = 0; k0 < 256; k0 += 32) {
#pragma unroll
    for (int r = 0; r < 4; ++r) {
      int row = arow + r * 64;
      *(uint4*)&Bs[row][akc] = *(const uint4*)(W1T + (size_t)row * 256 + k0 + akc);
    }
    __syncthreads();
    bf16x8 bfr[4];
#pragma unroll
    for (int ni = 0; ni < 4; ++ni)
      bfr[ni] = *(const bf16x8*)&Bs[wave * 64 + ni * 16 + l15][quad * 8];
#pragma unroll
    for (int mi = 0; mi < 4; ++mi) {
      bf16x8 af = *(const bf16x8*)&h0[mi * 16 + l15][k0 + quad * 8];
#pragma unroll
      for (int ni = 0; ni < 4; ++ni) acc2[mi][ni] = MFMA16(af, bfr[ni], acc2[mi][ni]);
    }
    __syncthreads();
  }
  float part[4][4];
#pragma unroll
  for (int mi = 0; mi < 4; ++mi)
#pragma unroll
    for (int r = 0; r < 4; ++r) part[mi][r] = 0.f;
#pragma unroll
  for (int mi = 0; mi < 4; ++mi)
#pragma unroll
    for (int ni = 0; ni < 4; ++ni) {
      int c = wave * 64 + ni * 16 + l15;
      float bv = b1[c], wv = W2[c];
#pragma unroll
      for (int r = 0; r < 4; ++r) {
        float v = fmaxf(acc2[mi][ni][r] + bv, 0.f);
        part[mi][r] += v * wv;
      }
    }
#pragma unroll
  for (int d = 1; d < 16; d <<= 1)
#pragma unroll
    for (int mi = 0; mi < 4; ++mi)
#pragma unroll
      for (int r = 0; r < 4; ++r) part[mi][r] += __shfl_xor(part[mi][r], d);
  if (l15 == 0)
#pragma unroll
    for (int mi = 0; mi < 4; ++mi)
#pragma unroll
      for (int r = 0; r < 4; ++r) red[wave][mi * 16 + quad * 4 + r] = part[mi][r];
  __syncthreads();
  if (tid < 64) {
    float s = red[0][tid] + red[1][tid] + red[2][tid] + red[3][tid];
    out[m0 + tid] = s + b2[0];
  }
}

// ---------------- host ----------------

extern "C" void kernel_launch(void* const* d_in, const int* in_sizes, int n_in,
                              void* d_out, int out_size, void* d_ws, size_t ws_size,
                              hipStream_t stream) {
  const int*   eidx1  = (const int*)d_in[0];
  const float* eattr1 = (const float*)d_in[1];
  const int*   eidx2  = (const int*)d_in[2];
  const float* eattr2 = (const float*)d_in[3];
  const int*   batch  = (const int*)d_in[4];
  const float* tval   = (const float*)d_in[5];
  const float* te_W0 = (const float*)d_in[6];
  const float* te_b0 = (const float*)d_in[7];
  const float* te_W1 = (const float*)d_in[8];
  const float* te_b1 = (const float*)d_in[9];
  const float* te_W2 = (const float*)d_in[10];
  const float* te_b2 = (const float*)d_in[11];
  const float* ee_W0 = (const float*)d_in[12];
  const float* ee_b0 = (const float*)d_in[13];
  const float* ee_W1 = (const float*)d_in[14];
  const float* ee_b1 = (const float*)d_in[15];
  const float* ee_W2 = (const float*)d_in[16];
  const float* ee_b2 = (const float*)d_in[17];
  const float* dec_W0 = (const float*)d_in[18];
  const float* dec_b0 = (const float*)d_in[19];
  const float* dec_W1 = (const float*)d_in[20];
  const float* dec_b1 = (const float*)d_in[21];
  const float* dec_W2 = (const float*)d_in[22];
  const float* dec_b2 = (const float*)d_in[23];
  const float* gg_Wl  = (const float*)d_in[24];
  const float* gg_bl  = (const float*)d_in[25];
  const float* gg_Wr  = (const float*)d_in[26];
  const float* gg_br  = (const float*)d_in[27];
  const float* gg_We  = (const float*)d_in[28];
  const float* gg_att = (const float*)d_in[29];
  const float* gg_bias= (const float*)d_in[30];
  const float* gf_Wl  = (const float*)d_in[31];
  const float* gf_bl  = (const float*)d_in[32];
  const float* gf_Wr  = (const float*)d_in[33];
  const float* gf_br  = (const float*)d_in[34];
  const float* gf_We  = (const float*)d_in[35];
  const float* gf_att = (const float*)d_in[36];
  const float* gf_bias= (const float*)d_in[37];
  (void)in_sizes; (void)n_in; (void)out_size; (void)ws_size;

  const int* src1 = eidx1;
  const int* dst1 = eidx1 + NE1;
  const int* src2 = eidx2;
  const int* dst2 = eidx2 + NE2;

  char* base = (char*)d_ws;
  size_t off = 0;
  auto alloc = [&](size_t bytes) {
    void* p = base + off;
    off += (bytes + 255) & ~(size_t)255;
    return p;
  };
  ushort* x_a    = (ushort*)alloc((size_t)NNODE * 512 * 2);
  ushort* x_b    = (ushort*)alloc((size_t)NNODE * 512 * 2);
  ushort* xlr    = (ushort*)alloc((size_t)NNODE * 512 * 2);
  ushort* e1     = (ushort*)alloc((size_t)NE1 * Hd * 2);
  ushort* e2     = (ushort*)alloc((size_t)NE2 * Hd * 2);
  float*  logits = (float*)alloc((size_t)NE1 * 4);
  float*  tenc   = (float*)alloc((size_t)16 * Hd * 4);
  ushort* eeW1T  = (ushort*)alloc((size_t)256 * 256 * 2);
  ushort* eeW2T  = (ushort*)alloc((size_t)256 * 256 * 2);
  ushort* decW0T = (ushort*)alloc((size_t)256 * 1280 * 2);
  ushort* decW1T = (ushort*)alloc((size_t)256 * 256 * 2);
  ushort* wlrT   = (ushort*)alloc((size_t)6 * 512 * 512 * 2);
  ushort* weT    = (ushort*)alloc((size_t)6 * 256 * 256 * 2);
  float*  biascat= (float*)alloc((size_t)6 * 512 * 4);
  int* cnt1      = (int*)alloc((size_t)NNODE * 4);
  int* cur1      = (int*)alloc((size_t)NNODE * 4);
  int* rs1       = (int*)alloc((size_t)(NNODE + 1) * 4);
  int* eid1      = (int*)alloc((size_t)NE1 * 4);
  int* cnt2      = (int*)alloc((size_t)NNODE * 4);
  int* cur2      = (int*)alloc((size_t)NNODE * 4);
  int* rs2       = (int*)alloc((size_t)(NNODE + 1) * 4);
  int* eid2      = (int*)alloc((size_t)NE2 * 4);

  float* out = (float*)d_out;
  const int NB = (NNODE + 255) / 256;

  // ---- CSR build (by dst), once per graph ----
  zero_k<<<NB, 256, 0, stream>>>(cnt1, NNODE);
  zero_k<<<NB, 256, 0, stream>>>(cur1, NNODE);
  zero_k<<<NB, 256, 0, stream>>>(cnt2, NNODE);
  zero_k<<<NB, 256, 0, stream>>>(cur2, NNODE);
  deg_k<<<NE1 / 256, 256, 0, stream>>>(dst1, cnt1, NE1);
  deg_k<<<NE2 / 256, 256, 0, stream>>>(dst2, cnt2, NE2);
  scan_k<<<1, 640, 0, stream>>>(cnt1, rs1, NE1);
  scan_k<<<1, 640, 0, stream>>>(cnt2, rs2, NE2);
  fill_k<<<NE1 / 256, 256, 0, stream>>>(dst1, rs1, cur1, eid1, NE1);
  fill_k<<<NE2 / 256, 256, 0, stream>>>(dst2, rs2, cur2, eid2, NE2);

  // ---- weight prep ----
  transpose_k<<<dim3(8, 8), 256, 0, stream>>>(ee_W1, eeW1T, 256, 0, 256);
  transpose_k<<<dim3(8, 8), 256, 0, stream>>>(ee_W2, eeW2T, 256, 0, 256);
  transpose_k<<<dim3(40, 8), 256, 0, stream>>>(dec_W0, decW0T, 1280, 0, 1280);
  transpose_k<<<dim3(8, 8), 256, 0, stream>>>(dec_W1, decW1T, 256, 0, 256);
  for (int i = 0; i < 3; ++i) {
    transpose_k<<<dim3(16, 8), 256, 0, stream>>>(gg_Wl + (size_t)i * 512 * 256, wlrT + (size_t)i * 512 * 512, 512, 0, 512);
    transpose_k<<<dim3(16, 8), 256, 0, stream>>>(gg_Wr + (size_t)i * 512 * 256, wlrT + (size_t)i * 512 * 512, 512, 256, 512);
    transpose_k<<<dim3(16, 8), 256, 0, stream>>>(gf_Wl + (size_t)i * 512 * 256, wlrT + (size_t)(3 + i) * 512 * 512, 512, 0, 512);
    transpose_k<<<dim3(16, 8), 256, 0, stream>>>(gf_Wr + (size_t)i * 512 * 256, wlrT + (size_t)(3 + i) * 512 * 512, 512, 256, 512);
    transpose_k<<<dim3(8, 8), 256, 0, stream>>>(gg_We + (size_t)i * 256 * 256, weT + (size_t)i * 256 * 256, 256, 0, 256);
    transpose_k<<<dim3(8, 8), 256, 0, stream>>>(gf_We + (size_t)i * 256 * 256, weT + (size_t)(3 + i) * 256 * 256, 256, 0, 256);
    cat512_k<<<2, 256, 0, stream>>>(gg_bl + i * 256, gg_br + i * 256, biascat + i * 512);
    cat512_k<<<2, 256, 0, stream>>>(gf_bl + i * 256, gf_br + i * 256, biascat + (3 + i) * 512);
  }

  // ---- fused edge encoder ----
  enc_fused_k<<<NE1 / 64, 256, 0, stream>>>(eattr1, ee_W0, ee_b0, eeW1T, ee_b1, eeW2T, ee_b2, e1);
  enc_fused_k<<<NE2 / 64, 256, 0, stream>>>(eattr2, ee_W0, ee_b0, eeW1T, ee_b1, eeW2T, ee_b2, e2);

  // ---- time encoding -> x0 (bf16) ----
  time_mlp_k<<<16, 256, 0, stream>>>(tval, te_W0, te_b0, te_W1, te_b1, te_W2, te_b2, tenc);
  build_x0_k<<<(NNODE * 512) / 256, 256, 0, stream>>>(batch, tenc, x_a);

  ushort* x_cur = x_a;
  ushort* x_nxt = x_b;
  const int ngrid = (NNODE + 63) / 64;
  const int agrid = (NNODE + 3) / 4;
  for (int i = 0; i < 3; ++i) {
    // ---- graph 1 ----
    mgemm_k<false, true><<<dim3(ngrid, 2), 256, 0, stream>>>(x_cur, 512, wlrT + (size_t)i * 512 * 512, 512, biascat + i * 512, xlr, 512, NNODE);
    attn_mfma_k<<<NE1 / 64, 256, 0, stream>>>(e1, weT + (size_t)i * 256 * 256, gg_att + i * Hd, xlr, src1, dst1, logits);
    aggregate_k<<<agrid, 256, 0, stream>>>(logits, xlr, src1, rs1, eid1, gg_bias + i * Hd, x_nxt, 0);
    // ---- graph 2 ----
    mgemm_k<false, true><<<dim3(ngrid, 2), 256, 0, stream>>>(x_cur, 512, wlrT + (size_t)(3 + i) * 512 * 512, 512, biascat + (3 + i) * 512, xlr, 512, NNODE);
    attn_mfma_k<<<NE2 / 64, 256, 0, stream>>>(e2, weT + (size_t)(3 + i) * 256 * 256, gf_att + i * Hd, xlr, src2, dst2, logits);
    aggregate_k<<<agrid, 256, 0, stream>>>(logits, xlr, src2, rs2, eid2, gf_bias + i * Hd, x_nxt, 256);
    ushort* t = x_cur; x_cur = x_nxt; x_nxt = t;
  }

  // ---- decoder ----
  dec_mfma_k<<<NE1 / 64, 256, 0, stream>>>(x_cur, e1, decW0T, dec_b0, decW1T, dec_b1,
                                           dec_W2, dec_b2, src1, dst1, out);
}

// Round 5
// 960.007 us; speedup vs baseline: 6.2447x; 1.1708x over previous
//
#include <hip/hip_runtime.h>

#define Hd 256
#define NNODE 10000
#define NE1 131072
#define NE2 65536

typedef __attribute__((ext_vector_type(8))) short bf16x8;
typedef __attribute__((ext_vector_type(4))) float f32x4;

#define MFMA16(a, b, c) __builtin_amdgcn_mfma_f32_16x16x32_bf16((a), (b), (c), 0, 0, 0)

__device__ __forceinline__ float b2f(ushort u) { return __uint_as_float(((unsigned)u) << 16); }
__device__ __forceinline__ ushort f2b(float f) {
  unsigned u = __float_as_uint(f);
  return (ushort)((u + 0x7fffu + ((u >> 16) & 1u)) >> 16);
}

// ---------------- small kernels ----------------

__global__ void time_mlp_k(const float* __restrict__ tval,
                           const float* __restrict__ W0, const float* __restrict__ b0,
                           const float* __restrict__ W1, const float* __restrict__ b1,
                           const float* __restrict__ W2, const float* __restrict__ b2,
                           float* __restrict__ tenc) {
  __shared__ float h0[Hd], h1[Hd];
  int b = blockIdx.x, j = threadIdx.x;
  float t = tval[b];
  h0[j] = fmaxf(t * W0[j] + b0[j], 0.f);
  __syncthreads();
  float a = b1[j];
  for (int k = 0; k < Hd; ++k) a += h0[k] * W1[k * Hd + j];
  h1[j] = fmaxf(a, 0.f);
  __syncthreads();
  float c = b2[j];
  for (int k = 0; k < Hd; ++k) c += h1[k] * W2[k * Hd + j];
  tenc[b * Hd + j] = c;
}

__global__ void build_x0_k(const int* __restrict__ batch, const float* __restrict__ tenc,
                           ushort* __restrict__ x0) {
  int idx = blockIdx.x * 256 + threadIdx.x;
  int n = idx >> 9;
  x0[idx] = f2b(tenc[batch[n] * Hd + (idx & 255)]);
}

// zero CSR counters + zero-bias + concat per-layer GAT biases (1024-wide)
__global__ void init_small_k(int* __restrict__ cnt1, int* __restrict__ cur1,
                             int* __restrict__ cnt2, int* __restrict__ cur2,
                             float* __restrict__ zerob, float* __restrict__ biascat,
                             const float* __restrict__ gg_bl, const float* __restrict__ gg_br,
                             const float* __restrict__ gf_bl, const float* __restrict__ gf_br) {
  int i = blockIdx.x * 256 + threadIdx.x;
  if (i < NNODE) { cnt1[i] = 0; cur1[i] = 0; cnt2[i] = 0; cur2[i] = 0; return; }
  i -= NNODE;
  if (i < 512) { zerob[i] = 0.f; return; }
  i -= 512;
  if (i < 6144) {
    int layer = i >> 10, c = i & 1023;
    float v;
    if (c < 256)      v = gg_bl[layer * 256 + c];
    else if (c < 512) v = gg_br[layer * 256 + c - 256];
    else if (c < 768) v = gf_bl[layer * 256 + c - 512];
    else              v = gf_br[layer * 256 + c - 768];
    biascat[layer * 1024 + c] = v;
  }
}

// ---------------- merged weight transposes ----------------
// fp32 [K][256] -> bf16 out[(n_off+n)*ld + k]
struct TT { const float* src; ushort* dst; int K; int n_off; int ld; int start; };
struct TransArgs { TT t[24]; };

__global__ void trans_all_k(TransArgs a) {
  int b = blockIdx.x;
  int ti = 0;
  while (ti + 1 < 24 && a.t[ti + 1].start <= b) ++ti;
  TT tk = a.t[ti];
  int lb = b - tk.start;
  int gx = tk.K >> 5;
  int k0 = (lb % gx) * 32, n0 = (lb / gx) * 32;
  __shared__ float t[32][33];
  int tx = threadIdx.x & 31, ty = threadIdx.x >> 5;
#pragma unroll
  for (int p = 0; p < 4; ++p)
    t[ty + 8 * p][tx] = tk.src[(size_t)(k0 + ty + 8 * p) * 256 + n0 + tx];
  __syncthreads();
#pragma unroll
  for (int p = 0; p < 4; ++p)
    tk.dst[(size_t)(tk.n_off + n0 + ty + 8 * p) * tk.ld + k0 + tx] = f2b(t[tx][ty + 8 * p]);
}

// ---------------- CSR build (by dst) ----------------

__global__ void deg_all_k(const int* __restrict__ dst1, int* __restrict__ cnt1,
                          const int* __restrict__ dst2, int* __restrict__ cnt2) {
  int e = blockIdx.x * 256 + threadIdx.x;
  if (e < NE1) atomicAdd(cnt1 + dst1[e], 1);
  else if (e - NE1 < NE2) atomicAdd(cnt2 + dst2[e - NE1], 1);
}

// grid 2, 640 threads; 625 x 16 = 10000 bins
__global__ void scan_k(const int* __restrict__ cnt1, int* __restrict__ rs1,
                       const int* __restrict__ cnt2, int* __restrict__ rs2) {
  const int g = blockIdx.x;
  const int* cnt = g ? cnt2 : cnt1;
  int* rowstart = g ? rs2 : rs1;
  const int E = g ? NE2 : NE1;
  __shared__ int part[626];
  int t = threadIdx.x;
  if (t < 625) {
    int s = 0;
#pragma unroll
    for (int i = 0; i < 16; ++i) s += cnt[t * 16 + i];
    part[t] = s;
  }
  __syncthreads();
  if (t == 0) {
    int run = 0;
    for (int i = 0; i < 625; ++i) { int v = part[i]; part[i] = run; run += v; }
  }
  __syncthreads();
  if (t < 625) {
    int off = part[t];
#pragma unroll
    for (int i = 0; i < 16; ++i) { rowstart[t * 16 + i] = off; off += cnt[t * 16 + i]; }
  }
  if (t == 0) rowstart[NNODE] = E;
}

__global__ void fill_all_k(const int* __restrict__ dst1, const int* __restrict__ rs1,
                           int* __restrict__ cur1, int* __restrict__ eid1,
                           const int* __restrict__ dst2, const int* __restrict__ rs2,
                           int* __restrict__ cur2, int* __restrict__ eid2) {
  int e = blockIdx.x * 256 + threadIdx.x;
  if (e < NE1) {
    int d = dst1[e];
    eid1[rs1[d] + atomicAdd(cur1 + d, 1)] = e;
  } else if (e - NE1 < NE2) {
    int e2 = e - NE1;
    int d = dst2[e2];
    eid2[rs2[d] + atomicAdd(cur2 + d, 1)] = e2;
  }
}

// ---------------- fused softmax + aggregate (one wave per node) ----------------
__global__ __launch_bounds__(256) void aggregate_k(
    const float* __restrict__ logits, const ushort* __restrict__ xl,  // + graph col offset
    const int* __restrict__ src, const int* __restrict__ rowstart,
    const int* __restrict__ eid, const float* __restrict__ bias,
    ushort* __restrict__ xnext, int colbase) {
  const int tid = threadIdx.x;
  const int wave = tid >> 6, lane = tid & 63;
  const int nid = blockIdx.x * 4 + wave;
  if (nid >= NNODE) return;
  const int s0 = rowstart[nid], s1 = rowstart[nid + 1];
  float mx = -__int_as_float(0x7f800000);
  for (int i = s0 + lane; i < s1; i += 64) mx = fmaxf(mx, logits[eid[i]]);
#pragma unroll
  for (int d = 1; d < 64; d <<= 1) mx = fmaxf(mx, __shfl_xor(mx, d));
  float den = 0.f;
  for (int i = s0 + lane; i < s1; i += 64) den += __expf(logits[eid[i]] - mx);
#pragma unroll
  for (int d = 1; d < 64; d <<= 1) den += __shfl_xor(den, d);
  float acc0 = 0.f, acc1 = 0.f, acc2 = 0.f, acc3 = 0.f;
  for (int i = s0; i < s1; ++i) {
    int e = eid[i];
    float w = __expf(logits[e] - mx);
    int s = src[e];
    ushort4 v = *(const ushort4*)(xl + (size_t)s * 1024 + lane * 4);
    acc0 += w * b2f(v.x); acc1 += w * b2f(v.y);
    acc2 += w * b2f(v.z); acc3 += w * b2f(v.w);
  }
  float inv = 1.f / (den + 1e-16f);
  int c = lane * 4;
  ushort4 o;
  o.x = f2b(acc0 * inv + bias[c + 0]);
  o.y = f2b(acc1 * inv + bias[c + 1]);
  o.z = f2b(acc2 * inv + bias[c + 2]);
  o.w = f2b(acc3 * inv + bias[c + 3]);
  *(ushort4*)(xnext + (size_t)nid * 512 + colbase + c) = o;
}

// ---------------- generic MFMA GEMM ----------------
// C[M, 256*gridDim.y] = op(A[M,K](bf16) @ W + bias), W given as WT[n][k] bf16.
template <bool RELU, bool OBF16>
__global__ __launch_bounds__(256, 2) void mgemm_k(
    const ushort* __restrict__ A, int lda, const ushort* __restrict__ WT, int K,
    const float* __restrict__ bias, void* __restrict__ C, int ldc, int M) {
  __shared__ ushort As[64][40];
  __shared__ ushort Bs[256][40];
  const int tid = threadIdx.x;
  const int wave = tid >> 6, lane = tid & 63;
  const int quad = lane >> 4, l15 = lane & 15;
  const int m0 = blockIdx.x * 64;
  const int ncol0 = blockIdx.y * 256;
  const ushort* WTb = WT + (size_t)ncol0 * K;
  const int arow = tid >> 2, akc = (tid & 3) << 3;
  int am = m0 + arow;
  if (am >= M) am = M - 1;
  f32x4 acc[4][4];
#pragma unroll
  for (int i = 0; i < 4; ++i)
#pragma unroll
    for (int j = 0; j < 4; ++j) acc[i][j] = (f32x4){0.f, 0.f, 0.f, 0.f};
  for (int k0 = 0; k0 < K; k0 += 32) {
    *(uint4*)&As[arow][akc] = *(const uint4*)(A + (size_t)am * lda + k0 + akc);
#pragma unroll
    for (int r = 0; r < 4; ++r) {
      int row = arow + r * 64;
      *(uint4*)&Bs[row][akc] = *(const uint4*)(WTb + (size_t)row * K + k0 + akc);
    }
    __syncthreads();
    bf16x8 bfr[4];
#pragma unroll
    for (int ni = 0; ni < 4; ++ni)
      bfr[ni] = *(const bf16x8*)&Bs[wave * 64 + ni * 16 + l15][quad * 8];
#pragma unroll
    for (int mi = 0; mi < 4; ++mi) {
      bf16x8 af = *(const bf16x8*)&As[mi * 16 + l15][quad * 8];
#pragma unroll
      for (int ni = 0; ni < 4; ++ni) acc[mi][ni] = MFMA16(af, bfr[ni], acc[mi][ni]);
    }
    __syncthreads();
  }
#pragma unroll
  for (int mi = 0; mi < 4; ++mi)
#pragma unroll
    for (int ni = 0; ni < 4; ++ni) {
      int c = ncol0 + wave * 64 + ni * 16 + l15;
      float bv = bias[c];
#pragma unroll
      for (int r = 0; r < 4; ++r) {
        int m = m0 + mi * 16 + quad * 4 + r;
        if (m < M) {
          float v = acc[mi][ni][r] + bv;
          if (RELU) v = fmaxf(v, 0.f);
          if (OBF16) ((ushort*)C)[(size_t)m * ldc + c] = f2b(v);
          else       ((float*)C)[(size_t)m * ldc + c] = v;
        }
      }
    }
}

// ---------------- fused edge-encoder MLP (64 edges / block) ----------------
__global__ __launch_bounds__(256, 2) void enc_fused_k(
    const float* __restrict__ attr, const float* __restrict__ W0,
    const float* __restrict__ b0, const ushort* __restrict__ W1T,
    const float* __restrict__ b1, const ushort* __restrict__ W2T,
    const float* __restrict__ b2, ushort* __restrict__ eout) {
  __shared__ ushort h[64][264];
  __shared__ ushort Bs[256][40];
  __shared__ float w0s[256], b0s[256];
  const int tid = threadIdx.x;
  const int wave = tid >> 6, lane = tid & 63;
  const int quad = lane >> 4, l15 = lane & 15;
  const int m0 = blockIdx.x * 64;
  const int arow = tid >> 2, akc = (tid & 3) << 3;
  w0s[tid] = W0[tid];
  b0s[tid] = b0[tid];
  float a0 = attr[m0 + arow];
  __syncthreads();
  {
    int c0 = (tid & 3) * 64;
#pragma unroll
    for (int j = 0; j < 64; j += 4) {
      int c = c0 + j;
      ushort4 o;
      o.x = f2b(fmaxf(a0 * w0s[c + 0] + b0s[c + 0], 0.f));
      o.y = f2b(fmaxf(a0 * w0s[c + 1] + b0s[c + 1], 0.f));
      o.z = f2b(fmaxf(a0 * w0s[c + 2] + b0s[c + 2], 0.f));
      o.w = f2b(fmaxf(a0 * w0s[c + 3] + b0s[c + 3], 0.f));
      *(ushort4*)&h[arow][c] = o;
    }
  }
  __syncthreads();
  f32x4 acc[4][4];
#pragma unroll
  for (int i = 0; i < 4; ++i)
#pragma unroll
    for (int j = 0; j < 4; ++j) acc[i][j] = (f32x4){0.f, 0.f, 0.f, 0.f};
  for (int k0 = 0; k0 < 256; k0 += 32) {
#pragma unroll
    for (int r = 0; r < 4; ++r) {
      int row = arow + r * 64;
      *(uint4*)&Bs[row][akc] = *(const uint4*)(W1T + (size_t)row * 256 + k0 + akc);
    }
    __syncthreads();
    bf16x8 bfr[4];
#pragma unroll
    for (int ni = 0; ni < 4; ++ni)
      bfr[ni] = *(const bf16x8*)&Bs[wave * 64 + ni * 16 + l15][quad * 8];
#pragma unroll
    for (int mi = 0; mi < 4; ++mi) {
      bf16x8 af = *(const bf16x8*)&h[mi * 16 + l15][k0 + quad * 8];
#pragma unroll
      for (int ni = 0; ni < 4; ++ni) acc[mi][ni] = MFMA16(af, bfr[ni], acc[mi][ni]);
    }
    __syncthreads();
  }
  __syncthreads();
#pragma unroll
  for (int mi = 0; mi < 4; ++mi)
#pragma unroll
    for (int ni = 0; ni < 4; ++ni) {
      int c = wave * 64 + ni * 16 + l15;
      float bv = b1[c];
#pragma unroll
      for (int r = 0; r < 4; ++r)
        h[mi * 16 + quad * 4 + r][c] = f2b(fmaxf(acc[mi][ni][r] + bv, 0.f));
    }
  __syncthreads();
  f32x4 acc2[4][4];
#pragma unroll
  for (int i = 0; i < 4; ++i)
#pragma unroll
    for (int j = 0; j < 4; ++j) acc2[i][j] = (f32x4){0.f, 0.f, 0.f, 0.f};
  for (int k0 = 0; k0 < 256; k0 += 32) {
#pragma unroll
    for (int r = 0; r < 4; ++r) {
      int row = arow + r * 64;
      *(uint4*)&Bs[row][akc] = *(const uint4*)(W2T + (size_t)row * 256 + k0 + akc);
    }
    __syncthreads();
    bf16x8 bfr[4];
#pragma unroll
    for (int ni = 0; ni < 4; ++ni)
      bfr[ni] = *(const bf16x8*)&Bs[wave * 64 + ni * 16 + l15][quad * 8];
#pragma unroll
    for (int mi = 0; mi < 4; ++mi) {
      bf16x8 af = *(const bf16x8*)&h[mi * 16 + l15][k0 + quad * 8];
#pragma unroll
      for (int ni = 0; ni < 4; ++ni) acc2[mi][ni] = MFMA16(af, bfr[ni], acc2[mi][ni]);
    }
    __syncthreads();
  }
#pragma unroll
  for (int mi = 0; mi < 4; ++mi)
#pragma unroll
    for (int ni = 0; ni < 4; ++ni) {
      int c = wave * 64 + ni * 16 + l15;
      float bv = b2[c];
#pragma unroll
      for (int r = 0; r < 4; ++r) {
        int m = m0 + mi * 16 + quad * 4 + r;
        eout[(size_t)m * 256 + c] = f2b(acc2[mi][ni][r] + bv);
      }
    }
}

// ---------------- fused MFMA attention logits ----------------
// logit_e = att . leakyrelu( xl[src] + xr[dst] + e@We ),  64 edges/block.
// xlr has ld 1024; graph offset pre-applied by caller.
__global__ __launch_bounds__(256, 2) void attn_mfma_k(
    const ushort* __restrict__ eenc, const ushort* __restrict__ weT,
    const float* __restrict__ att, const ushort* __restrict__ xlr,
    const int* __restrict__ src, const int* __restrict__ dst,
    float* __restrict__ logits) {
  __shared__ ushort As[64][40];
  __shared__ ushort Bs[256][40];
  __shared__ ushort xs[64][264];
  __shared__ float red[4][64];
  __shared__ float att_s[256];
  const int tid = threadIdx.x;
  const int wave = tid >> 6, lane = tid & 63;
  const int quad = lane >> 4, l15 = lane & 15;
  const int m0 = blockIdx.x * 64;
  const int arow = tid >> 2, akc = (tid & 3) << 3;
  att_s[tid] = att[tid];
  {
    int s = src[m0 + arow], d = dst[m0 + arow];
    int c0 = (tid & 3) * 64;
    const ushort* pl = xlr + (size_t)s * 1024;
    const ushort* pr = xlr + (size_t)d * 1024 + 256;
#pragma unroll
    for (int j = 0; j < 16; ++j) {
      int c = c0 + 4 * j;
      ushort4 a = *(const ushort4*)(pl + c);
      ushort4 b = *(const ushort4*)(pr + c);
      ushort4 o;
      o.x = f2b(b2f(a.x) + b2f(b.x)); o.y = f2b(b2f(a.y) + b2f(b.y));
      o.z = f2b(b2f(a.z) + b2f(b.z)); o.w = f2b(b2f(a.w) + b2f(b.w));
      *(ushort4*)&xs[arow][c] = o;
    }
  }
  f32x4 acc[4][4];
#pragma unroll
  for (int i = 0; i < 4; ++i)
#pragma unroll
    for (int j = 0; j < 4; ++j) acc[i][j] = (f32x4){0.f, 0.f, 0.f, 0.f};
  for (int k0 = 0; k0 < 256; k0 += 32) {
    *(uint4*)&As[arow][akc] = *(const uint4*)(eenc + (size_t)(m0 + arow) * 256 + k0 + akc);
#pragma unroll
    for (int r = 0; r < 4; ++r) {
      int row = arow + r * 64;
      *(uint4*)&Bs[row][akc] = *(const uint4*)(weT + (size_t)row * 256 + k0 + akc);
    }
    __syncthreads();
    bf16x8 bfr[4];
#pragma unroll
    for (int ni = 0; ni < 4; ++ni)
      bfr[ni] = *(const bf16x8*)&Bs[wave * 64 + ni * 16 + l15][quad * 8];
#pragma unroll
    for (int mi = 0; mi < 4; ++mi) {
      bf16x8 af = *(const bf16x8*)&As[mi * 16 + l15][quad * 8];
#pragma unroll
      for (int ni = 0; ni < 4; ++ni) acc[mi][ni] = MFMA16(af, bfr[ni], acc[mi][ni]);
    }
    __syncthreads();
  }
  float part[4][4];
#pragma unroll
  for (int mi = 0; mi < 4; ++mi)
#pragma unroll
    for (int r = 0; r < 4; ++r) part[mi][r] = 0.f;
#pragma unroll
  for (int mi = 0; mi < 4; ++mi)
#pragma unroll
    for (int ni = 0; ni < 4; ++ni) {
      int c = wave * 64 + ni * 16 + l15;
      float av = att_s[c];
#pragma unroll
      for (int r = 0; r < 4; ++r) {
        int row = mi * 16 + quad * 4 + r;
        float v = acc[mi][ni][r] + b2f(xs[row][c]);
        v = v > 0.f ? v : 0.2f * v;
        part[mi][r] += v * av;
      }
    }
#pragma unroll
  for (int d = 1; d < 16; d <<= 1)
#pragma unroll
    for (int mi = 0; mi < 4; ++mi)
#pragma unroll
      for (int r = 0; r < 4; ++r) part[mi][r] += __shfl_xor(part[mi][r], d);
  if (l15 == 0)
#pragma unroll
    for (int mi = 0; mi < 4; ++mi)
#pragma unroll
      for (int r = 0; r < 4; ++r) red[wave][mi * 16 + quad * 4 + r] = part[mi][r];
  __syncthreads();
  if (tid < 64)
    logits[m0 + tid] = red[0][tid] + red[1][tid] + red[2][tid] + red[3][tid];
}

// ---------------- decomposed MFMA decoder ----------------
// h0 = relu(Za[src] + Zb[dst] + e1@W0c + b0); h1 = relu(h0@W1+b1); out = h1.W2 + b2
__global__ __launch_bounds__(256, 2) void dec2_k(
    const ushort* __restrict__ e1, const ushort* __restrict__ W0cT,
    const float* __restrict__ Z, const float* __restrict__ b0,
    const ushort* __restrict__ W1T, const float* __restrict__ b1,
    const float* __restrict__ W2, const float* __restrict__ b2,
    const int* __restrict__ src, const int* __restrict__ dst,
    float* __restrict__ out) {
  __shared__ ushort As[64][40];
  __shared__ ushort Bs[256][40];
  __shared__ ushort h0[64][264];
  __shared__ float red[4][64];
  const int tid = threadIdx.x;
  const int wave = tid >> 6, lane = tid & 63;
  const int quad = lane >> 4, l15 = lane & 15;
  const int m0 = blockIdx.x * 64;
  const int arow = tid >> 2, akc = (tid & 3) << 3;
  {  // pre-stage h0 = bf16(Za[src] + Zb[dst])
    int gs = src[m0 + arow], gd = dst[m0 + arow];
    int c0 = (tid & 3) * 64;
    const float* za = Z + (size_t)gs * 512;
    const float* zb = Z + (size_t)gd * 512 + 256;
#pragma unroll
    for (int j = 0; j < 16; ++j) {
      int c = c0 + 4 * j;
      float4 a = *(const float4*)(za + c);
      float4 b = *(const float4*)(zb + c);
      ushort4 o;
      o.x = f2b(a.x + b.x); o.y = f2b(a.y + b.y);
      o.z = f2b(a.z + b.z); o.w = f2b(a.w + b.w);
      *(ushort4*)&h0[arow][c] = o;
    }
  }
  f32x4 acc[4][4];
#pragma unroll
  for (int i = 0; i < 4; ++i)
#pragma unroll
    for (int j = 0; j < 4; ++j) acc[i][j] = (f32x4){0.f, 0.f, 0.f, 0.f};
  // phase 1: acc = e1 @ W0c   (K=256)
  for (int k0 = 0; k0 < 256; k0 += 32) {
    *(uint4*)&As[arow][akc] = *(const uint4*)(e1 + (size_t)(m0 + arow) * 256 + k0 + akc);
#pragma unroll
    for (int r = 0; r < 4; ++r) {
      int row = arow + r * 64;
      *(uint4*)&Bs[row][akc] = *(const uint4*)(W0cT + (size_t)row * 256 + k0 + akc);
    }
    __syncthreads();
    bf16x8 bfr[4];
#pragma unroll
    for (int ni = 0; ni < 4; ++ni)
      bfr[ni] = *(const bf16x8*)&Bs[wave * 64 + ni * 16 + l15][quad * 8];
#pragma unroll
    for (int mi = 0; mi < 4; ++mi) {
      bf16x8 af = *(const bf16x8*)&As[mi * 16 + l15][quad * 8];
#pragma unroll
      for (int ni = 0; ni < 4; ++ni) acc[mi][ni] = MFMA16(af, bfr[ni], acc[mi][ni]);
    }
    __syncthreads();
  }
  // epilogue phase 1: h0 = relu(acc + h0 + b0)   (each cell touched by one thread)
#pragma unroll
  for (int mi = 0; mi < 4; ++mi)
#pragma unroll
    for (int ni = 0; ni < 4; ++ni) {
      int c = wave * 64 + ni * 16 + l15;
      float bv = b0[c];
#pragma unroll
      for (int r = 0; r < 4; ++r) {
        int row = mi * 16 + quad * 4 + r;
        h0[row][c] = f2b(fmaxf(acc[mi][ni][r] + b2f(h0[row][c]) + bv, 0.f));
      }
    }
  __syncthreads();
  // phase 2
  f32x4 acc2[4][4];
#pragma unroll
  for (int i = 0; i < 4; ++i)
#pragma unroll
    for (int j = 0; j < 4; ++j) acc2[i][j] = (f32x4){0.f, 0.f, 0.f, 0.f};
  for (int k0 = 0; k0 < 256; k0 += 32) {
#pragma unroll
    for (int r = 0; r < 4; ++r) {
      int row = arow + r * 64;
      *(uint4*)&Bs[row][akc] = *(const uint4*)(W1T + (size_t)row * 256 + k0 + akc);
    }
    __syncthreads();
    bf16x8 bfr[4];
#pragma unroll
    for (int ni = 0; ni < 4; ++ni)
      bfr[ni] = *(const bf16x8*)&Bs[wave * 64 + ni * 16 + l15][quad * 8];
#pragma unroll
    for (int mi = 0; mi < 4; ++mi) {
      bf16x8 af = *(const bf16x8*)&h0[mi * 16 + l15][k0 + quad * 8];
#pragma unroll
      for (int ni = 0; ni < 4; ++ni) acc2[mi][ni] = MFMA16(af, bfr[ni], acc2[mi][ni]);
    }
    __syncthreads();
  }
  float part[4][4];
#pragma unroll
  for (int mi = 0; mi < 4; ++mi)
#pragma unroll
    for (int r = 0; r < 4; ++r) part[mi][r] = 0.f;
#pragma unroll
  for (int mi = 0; mi < 4; ++mi)
#pragma unroll
    for (int ni = 0; ni < 4; ++ni) {
      int c = wave * 64 + ni * 16 + l15;
      float bv = b1[c], wv = W2[c];
#pragma unroll
      for (int r = 0; r < 4; ++r) {
        float v = fmaxf(acc2[mi][ni][r] + bv, 0.f);
        part[mi][r] += v * wv;
      }
    }
#pragma unroll
  for (int d = 1; d < 16; d <<= 1)
#pragma unroll
    for (int mi = 0; mi < 4; ++mi)
#pragma unroll
      for (int r = 0; r < 4; ++r) part[mi][r] += __shfl_xor(part[mi][r], d);
  if (l15 == 0)
#pragma unroll
    for (int mi = 0; mi < 4; ++mi)
#pragma unroll
      for (int r = 0; r < 4; ++r) red[wave][mi * 16 + quad * 4 + r] = part[mi][r];
  __syncthreads();
  if (tid < 64) {
    float s = red[0][tid] + red[1][tid] + red[2][tid] + red[3][tid];
    out[m0 + tid] = s + b2[0];
  }
}

// ---------------- host ----------------

extern "C" void kernel_launch(void* const* d_in, const int* in_sizes, int n_in,
                              void* d_out, int out_size, void* d_ws, size_t ws_size,
                              hipStream_t stream) {
  const int*   eidx1  = (const int*)d_in[0];
  const float* eattr1 = (const float*)d_in[1];
  const int*   eidx2  = (const int*)d_in[2];
  const float* eattr2 = (const float*)d_in[3];
  const int*   batch  = (const int*)d_in[4];
  const float* tval   = (const float*)d_in[5];
  const float* te_W0 = (const float*)d_in[6];
  const float* te_b0 = (const float*)d_in[7];
  const float* te_W1 = (const float*)d_in[8];
  const float* te_b1 = (const float*)d_in[9];
  const float* te_W2 = (const float*)d_in[10];
  const float* te_b2 = (const float*)d_in[11];
  const float* ee_W0 = (const float*)d_in[12];
  const float* ee_b0 = (const float*)d_in[13];
  const float* ee_W1 = (const float*)d_in[14];
  const float* ee_b1 = (const float*)d_in[15];
  const float* ee_W2 = (const float*)d_in[16];
  const float* ee_b2 = (const float*)d_in[17];
  const float* dec_W0 = (const float*)d_in[18];
  const float* dec_b0 = (const float*)d_in[19];
  const float* dec_W1 = (const float*)d_in[20];
  const float* dec_b1 = (const float*)d_in[21];
  const float* dec_W2 = (const float*)d_in[22];
  const float* dec_b2 = (const float*)d_in[23];
  const float* gg_Wl  = (const float*)d_in[24];
  const float* gg_bl  = (const float*)d_in[25];
  const float* gg_Wr  = (const float*)d_in[26];
  const float* gg_br  = (const float*)d_in[27];
  const float* gg_We  = (const float*)d_in[28];
  const float* gg_att = (const float*)d_in[29];
  const float* gg_bias= (const float*)d_in[30];
  const float* gf_Wl  = (const float*)d_in[31];
  const float* gf_bl  = (const float*)d_in[32];
  const float* gf_Wr  = (const float*)d_in[33];
  const float* gf_br  = (const float*)d_in[34];
  const float* gf_We  = (const float*)d_in[35];
  const float* gf_att = (const float*)d_in[36];
  const float* gf_bias= (const float*)d_in[37];
  (void)in_sizes; (void)n_in; (void)out_size; (void)ws_size;

  const int* src1 = eidx1;
  const int* dst1 = eidx1 + NE1;
  const int* src2 = eidx2;
  const int* dst2 = eidx2 + NE2;

  char* base = (char*)d_ws;
  size_t off = 0;
  auto alloc = [&](size_t bytes) {
    void* p = base + off;
    off += (bytes + 255) & ~(size_t)255;
    return p;
  };
  ushort* x_a    = (ushort*)alloc((size_t)NNODE * 512 * 2);
  ushort* x_b    = (ushort*)alloc((size_t)NNODE * 512 * 2);
  ushort* xlr    = (ushort*)alloc((size_t)NNODE * 1024 * 2);
  float*  Z      = (float*)alloc((size_t)NNODE * 512 * 4);
  ushort* e1     = (ushort*)alloc((size_t)NE1 * Hd * 2);
  ushort* e2     = (ushort*)alloc((size_t)NE2 * Hd * 2);
  float*  logits = (float*)alloc((size_t)NE1 * 4);
  float*  tenc   = (float*)alloc((size_t)16 * Hd * 4);
  ushort* eeW1T  = (ushort*)alloc((size_t)256 * 256 * 2);
  ushort* eeW2T  = (ushort*)alloc((size_t)256 * 256 * 2);
  ushort* decZT  = (ushort*)alloc((size_t)512 * 512 * 2);
  ushort* decW0cT= (ushort*)alloc((size_t)256 * 256 * 2);
  ushort* decW1T = (ushort*)alloc((size_t)256 * 256 * 2);
  ushort* wlrT   = (ushort*)alloc((size_t)6 * 512 * 512 * 2);  // [2*i+g]
  ushort* weT    = (ushort*)alloc((size_t)6 * 256 * 256 * 2);  // [2*i+g]
  float*  biascat= (float*)alloc((size_t)6 * 1024 * 4);        // [i][g*512 ...]
  float*  zerob  = (float*)alloc((size_t)512 * 4);
  int* cnt1      = (int*)alloc((size_t)NNODE * 4);
  int* cur1      = (int*)alloc((size_t)NNODE * 4);
  int* rs1       = (int*)alloc((size_t)(NNODE + 1) * 4);
  int* eid1      = (int*)alloc((size_t)NE1 * 4);
  int* cnt2      = (int*)alloc((size_t)NNODE * 4);
  int* cur2      = (int*)alloc((size_t)NNODE * 4);
  int* rs2       = (int*)alloc((size_t)(NNODE + 1) * 4);
  int* eid2      = (int*)alloc((size_t)NE2 * 4);

  float* out = (float*)d_out;

  // ---- merged setup: zeros + bias concat ----
  init_small_k<<<(NNODE + 512 + 6144 + 255) / 256, 256, 0, stream>>>(
      cnt1, cur1, cnt2, cur2, zerob, biascat, gg_bl, gg_br, gf_bl, gf_br);

  // ---- merged weight transposes ----
  TransArgs ta;
  int nt = 0, cum = 0;
  auto add = [&](const float* s, ushort* d, int K, int noff, int ld) {
    ta.t[nt].src = s; ta.t[nt].dst = d; ta.t[nt].K = K;
    ta.t[nt].n_off = noff; ta.t[nt].ld = ld; ta.t[nt].start = cum;
    cum += (K / 32) * 8; ++nt;
  };
  add(ee_W1, eeW1T, 256, 0, 256);
  add(ee_W2, eeW2T, 256, 0, 256);
  add(dec_W1, decW1T, 256, 0, 256);
  add(dec_W0, decZT, 512, 0, 512);
  add(dec_W0 + 512 * 256, decZT, 512, 256, 512);
  add(dec_W0 + 1024 * 256, decW0cT, 256, 0, 256);
  for (int i = 0; i < 3; ++i) {
    add(gg_Wl + (size_t)i * 512 * 256, wlrT + (size_t)(2 * i) * 512 * 512, 512, 0, 512);
    add(gg_Wr + (size_t)i * 512 * 256, wlrT + (size_t)(2 * i) * 512 * 512, 512, 256, 512);
    add(gf_Wl + (size_t)i * 512 * 256, wlrT + (size_t)(2 * i + 1) * 512 * 512, 512, 0, 512);
    add(gf_Wr + (size_t)i * 512 * 256, wlrT + (size_t)(2 * i + 1) * 512 * 512, 512, 256, 512);
    add(gg_We + (size_t)i * 65536, weT + (size_t)(2 * i) * 65536, 256, 0, 256);
    add(gf_We + (size_t)i * 65536, weT + (size_t)(2 * i + 1) * 65536, 256, 0, 256);
  }
  trans_all_k<<<cum, 256, 0, stream>>>(ta);

  // ---- CSR build (by dst) ----
  deg_all_k<<<(NE1 + NE2) / 256, 256, 0, stream>>>(dst1, cnt1, dst2, cnt2);
  scan_k<<<2, 640, 0, stream>>>(cnt1, rs1, cnt2, rs2);
  fill_all_k<<<(NE1 + NE2) / 256, 256, 0, stream>>>(dst1, rs1, cur1, eid1, dst2, rs2, cur2, eid2);

  // ---- fused edge encoder ----
  enc_fused_k<<<NE1 / 64, 256, 0, stream>>>(eattr1, ee_W0, ee_b0, eeW1T, ee_b1, eeW2T, ee_b2, e1);
  enc_fused_k<<<NE2 / 64, 256, 0, stream>>>(eattr2, ee_W0, ee_b0, eeW1T, ee_b1, eeW2T, ee_b2, e2);

  // ---- time encoding -> x0 (bf16) ----
  time_mlp_k<<<16, 256, 0, stream>>>(tval, te_W0, te_b0, te_W1, te_b1, te_W2, te_b2, tenc);
  build_x0_k<<<(NNODE * 512) / 256, 256, 0, stream>>>(batch, tenc, x_a);

  ushort* x_cur = x_a;
  ushort* x_nxt = x_b;
  const int ngrid = (NNODE + 63) / 64;
  const int agrid = (NNODE + 3) / 4;
  for (int i = 0; i < 3; ++i) {
    // xlr (both graphs): cols 0..511 = graph1 [xl|xr], 512..1023 = graph2
    mgemm_k<false, true><<<dim3(ngrid, 4), 256, 0, stream>>>(
        x_cur, 512, wlrT + (size_t)(2 * i) * 512 * 512, 512, biascat + (size_t)i * 1024, xlr, 1024, NNODE);
    attn_mfma_k<<<NE1 / 64, 256, 0, stream>>>(e1, weT + (size_t)(2 * i) * 65536, gg_att + i * Hd,
                                              xlr, src1, dst1, logits);
    aggregate_k<<<agrid, 256, 0, stream>>>(logits, xlr, src1, rs1, eid1, gg_bias + i * Hd, x_nxt, 0);
    attn_mfma_k<<<NE2 / 64, 256, 0, stream>>>(e2, weT + (size_t)(2 * i + 1) * 65536, gf_att + i * Hd,
                                              xlr + 512, src2, dst2, logits);
    aggregate_k<<<agrid, 256, 0, stream>>>(logits, xlr + 512, src2, rs2, eid2, gf_bias + i * Hd, x_nxt, 256);
    ushort* t = x_cur; x_cur = x_nxt; x_nxt = t;
  }

  // ---- decoder: Z = x @ [W0a|W0b] (per-node), then per-edge fused MLP ----
  mgemm_k<false, false><<<dim3(ngrid, 2), 256, 0, stream>>>(
      x_cur, 512, decZT, 512, zerob, Z, 512, NNODE);
  dec2_k<<<NE1 / 64, 256, 0, stream>>>(e1, decW0cT, Z, dec_b0, decW1T, dec_b1,
                                       dec_W2, dec_b2, src1, dst1, out);
}